// Round 3
// baseline (4747.328 us; speedup 1.0000x reference)
//
#include <hip/hip_runtime.h>
#include <hip/hip_bf16.h>
#include <cstddef>

#define NRB 100000      // robot nodes
#define NBL 100000      // ball nodes
#define NEDGE 600000    // edges per edge type
// dims: 128 -> 128 -> 64
// NOTE: harness delivers integer inputs as int32 (edge indices are const int*).

// ---------------- small kernels ----------------

__global__ __launch_bounds__(256) void count_kernel(const int* __restrict__ ei,
                                                    float* __restrict__ cnt) {
    int e = blockIdx.x * 256 + threadIdx.x;
    if (e < NEDGE) {
        int dst = ei[NEDGE + e];
        atomicAdd(&cnt[dst], 1.0f);
    }
}

__global__ __launch_bounds__(256) void inv_kernel(const float* __restrict__ cnt,
                                                  float* __restrict__ inv, int n) {
    int i = blockIdx.x * 256 + threadIdx.x;
    if (i < n) inv[i] = 1.0f / fmaxf(cnt[i], 1.0f);
}

__global__ __launch_bounds__(256) void vecadd_kernel(const float* __restrict__ a,
                                                     const float* __restrict__ b,
                                                     float* __restrict__ c, int n) {
    int i = blockIdx.x * 256 + threadIdx.x;
    if (i < n) c[i] = a[i] + b[i];
}

// acc[dst] += inv[dst] * y[src], y is [*,128] bf16. 32 threads/edge, 4 elems each.
__global__ __launch_bounds__(256) void scatter128bf_kernel(const __hip_bfloat16* __restrict__ y,
                                                           const int* __restrict__ ei,
                                                           const float* __restrict__ inv,
                                                           float* __restrict__ acc) {
    int tid = blockIdx.x * 256 + threadIdx.x;
    int e = tid >> 5;
    int c = tid & 31;
    if (e >= NEDGE) return;
    int src = ei[e];
    int dst = ei[NEDGE + e];
    float s = inv[dst];
    const __hip_bfloat162* yp = (const __hip_bfloat162*)(y + (size_t)src * 128 + c * 4);
    float2 fa = __bfloat1622float2(yp[0]);
    float2 fb = __bfloat1622float2(yp[1]);
    float* p = acc + (size_t)dst * 128 + c * 4;
    atomicAdd(p + 0, s * fa.x);
    atomicAdd(p + 1, s * fa.y);
    atomicAdd(p + 2, s * fb.x);
    atomicAdd(p + 3, s * fb.y);
}

// out[dst] += inv[dst] * z[src], z is [*,64] bf16. 16 threads/edge, 4 elems each.
__global__ __launch_bounds__(256) void scatter64bf_kernel(const __hip_bfloat16* __restrict__ z,
                                                          const int* __restrict__ ei,
                                                          const float* __restrict__ inv,
                                                          float* __restrict__ out) {
    int tid = blockIdx.x * 256 + threadIdx.x;
    int e = tid >> 4;
    int c = tid & 15;
    if (e >= NEDGE) return;
    int src = ei[e];
    int dst = ei[NEDGE + e];
    float s = inv[dst];
    const __hip_bfloat162* zp = (const __hip_bfloat162*)(z + (size_t)src * 64 + c * 4);
    float2 fa = __bfloat1622float2(zp[0]);
    float2 fb = __bfloat1622float2(zp[1]);
    float* p = out + (size_t)dst * 64 + c * 4;
    atomicAdd(p + 0, s * fa.x);
    atomicAdd(p + 1, s * fa.y);
    atomicAdd(p + 2, s * fb.x);
    atomicAdd(p + 3, s * fb.y);
}

// ---------------- fused GEMM ----------------
// out[M,BN] = act( A @ W  (+ X0)  (+ bias) ), A is [M,128] fp32, W is [128,BN].
// BM=64, BK=16, 256 threads, thread tile 4 x (BN/16).
__device__ inline void store_out(float* p, float v) { *p = v; }
__device__ inline void store_out(__hip_bfloat16* p, float v) { *p = __float2bfloat16(v); }

template<int BN, bool WITH_X, bool RELU, typename OutT>
__global__ __launch_bounds__(256) void gemm_kernel(
    int M,
    const float* __restrict__ A, const float* __restrict__ W,
    const float* __restrict__ X0,
    const float* __restrict__ bias, OutT* __restrict__ out)
{
    const int TN = BN / 16;            // 8 (BN=128) or 4 (BN=64)
    __shared__ float As[16][68];       // padded leading dim
    __shared__ float Ws[16][BN];

    float acc[4][TN];
    #pragma unroll
    for (int i = 0; i < 4; ++i)
        #pragma unroll
        for (int j = 0; j < TN; ++j) acc[i][j] = 0.0f;

    const int row0 = blockIdx.x * 64;
    const int tid = threadIdx.x;
    const int tx = tid & 15;   // column group
    const int ty = tid >> 4;   // row group (0..15), 4 rows each
    const int lm = tid >> 2;   // A-load row 0..63
    const int lc = tid & 3;    // A-load k chunk
    const int gr = row0 + lm;

    for (int kb = 0; kb < 128; kb += 16) {
        float4 av = make_float4(0.f, 0.f, 0.f, 0.f);
        if (gr < M) av = *(const float4*)(A + (size_t)gr * 128 + kb + lc * 4);
        As[lc * 4 + 0][lm] = av.x;
        As[lc * 4 + 1][lm] = av.y;
        As[lc * 4 + 2][lm] = av.z;
        As[lc * 4 + 3][lm] = av.w;

        const int NL = (BN * 16) / (256 * 4);   // float4 loads per thread: 2 or 1
        #pragma unroll
        for (int i = 0; i < NL; ++i) {
            int f = tid + i * 256;
            int k = f / (BN / 4);
            int c4 = f % (BN / 4);
            *(float4*)&Ws[k][c4 * 4] = *(const float4*)(W + (size_t)(kb + k) * BN + c4 * 4);
        }
        __syncthreads();

        #pragma unroll
        for (int k = 0; k < 16; ++k) {
            float4 a4 = *(const float4*)&As[k][ty * 4];
            float a[4] = {a4.x, a4.y, a4.z, a4.w};
            float b[TN];
            #pragma unroll
            for (int j = 0; j < TN; j += 4) {
                float4 b4 = *(const float4*)&Ws[k][tx * TN + j];
                b[j] = b4.x; b[j + 1] = b4.y; b[j + 2] = b4.z; b[j + 3] = b4.w;
            }
            #pragma unroll
            for (int i = 0; i < 4; ++i)
                #pragma unroll
                for (int j = 0; j < TN; ++j)
                    acc[i][j] += a[i] * b[j];
        }
        __syncthreads();
    }

    #pragma unroll
    for (int i = 0; i < 4; ++i) {
        int r = row0 + ty * 4 + i;
        if (r >= M) continue;
        #pragma unroll
        for (int j = 0; j < TN; ++j) {
            int col = tx * TN + j;
            float v = acc[i][j];
            if (WITH_X) v += X0[(size_t)r * BN + col];
            if (bias != nullptr) v += bias[col];
            if (RELU) v = fmaxf(v, 0.0f);
            store_out(&out[(size_t)r * BN + col], v);
        }
    }
}

// ---------------- launch ----------------
// Workspace (~105 MB):
//   BA  [NRB*128] bf16  25.6 MB — transform scratch (y_rb / y_rr / y_br), then z_rr
//   BB  [NRB*128] fp32  51.2 MB — accumulator -> bl -> accumulator -> r (in place)
//   z_br [NBL*64] bf16  12.8 MB
//   counts/invs 6*100k fp32 2.4 MB, weight sums ~0.1 MB

extern "C" void kernel_launch(void* const* d_in, const int* in_sizes, int n_in,
                              void* d_out, int out_size, void* d_ws, size_t ws_size,
                              hipStream_t stream) {
    (void)in_sizes; (void)n_in; (void)out_size; (void)ws_size;

    const float* x_robot = (const float*)d_in[0];
    const float* x_ball  = (const float*)d_in[1];
    const int* ei_rr = (const int*)d_in[2];   // [2, E] int32
    const int* ei_rb = (const int*)d_in[3];
    const int* ei_br = (const int*)d_in[4];
    const float* Wl0_rr = (const float*)d_in[5];
    const float* Wr0_rr = (const float*)d_in[6];
    const float* b0_rr  = (const float*)d_in[7];
    const float* Wl0_rb = (const float*)d_in[8];
    const float* Wr0_rb = (const float*)d_in[9];
    const float* b0_rb  = (const float*)d_in[10];
    const float* Wl0_br = (const float*)d_in[11];
    const float* Wr0_br = (const float*)d_in[12];
    const float* b0_br  = (const float*)d_in[13];
    const float* Wl1_rr = (const float*)d_in[14];
    const float* Wr1_rr = (const float*)d_in[15];
    const float* b1_rr  = (const float*)d_in[16];
    // d_in[17..19] = Wl1_rb / Wr1_rb / b1_rb — unused (ball output not returned)
    const float* Wl1_br = (const float*)d_in[20];
    const float* Wr1_br = (const float*)d_in[21];
    const float* b1_br  = (const float*)d_in[22];

    const size_t NBIG = (size_t)NRB * 128;   // 12.8M elems
    __hip_bfloat16* BA = (__hip_bfloat16*)d_ws;              // NBIG bf16
    float* BB = (float*)(BA + NBIG);                          // NBIG fp32
    __hip_bfloat16* z_br = (__hip_bfloat16*)(BB + NBIG);      // NBL*64 bf16
    float* cnt_rr = (float*)(z_br + (size_t)NBL * 64);
    float* cnt_br = cnt_rr + NRB;
    float* cnt_rb = cnt_br + NRB;
    float* inv_rr = cnt_rb + NBL;
    float* inv_br = inv_rr + NRB;
    float* inv_rb = inv_br + NRB;
    float* Wsum0 = inv_rb + NBL;      // 128x128
    float* bsum0 = Wsum0 + 128 * 128; // 128
    float* Wsum1 = bsum0 + 128;       // 128x64
    float* bsum1 = Wsum1 + 128 * 64;  // 64
    __hip_bfloat16* z_rr = BA;        // reuse BA after r is final

    hipMemsetAsync(cnt_rr, 0, (size_t)(NRB + NRB + NBL) * sizeof(float), stream);

    const int cblocks = (NEDGE + 255) / 256;
    count_kernel<<<cblocks, 256, 0, stream>>>(ei_rr, cnt_rr);
    count_kernel<<<cblocks, 256, 0, stream>>>(ei_br, cnt_br);
    count_kernel<<<cblocks, 256, 0, stream>>>(ei_rb, cnt_rb);
    inv_kernel<<<(3 * NRB + 255) / 256, 256, 0, stream>>>(cnt_rr, inv_rr, 3 * NRB);

    // weight sums (HeteroConv aggr='sum' folds the two robot-dst self terms)
    vecadd_kernel<<<(16384 + 255) / 256, 256, 0, stream>>>(Wr0_rr, Wr0_br, Wsum0, 16384);
    vecadd_kernel<<<1, 256, 0, stream>>>(b0_rr, b0_br, bsum0, 128);
    vecadd_kernel<<<(8192 + 255) / 256, 256, 0, stream>>>(Wr1_rr, Wr1_br, Wsum1, 8192);
    vecadd_kernel<<<1, 256, 0, stream>>>(b1_rr, b1_br, bsum1, 64);

    const int gblocks = (NRB + 63) / 64;
    const int sblocks128 = (NEDGE * 32 + 255) / 256;
    const int sblocks64  = (NEDGE * 16 + 255) / 256;

    // ---- ball path ----
    // BA = bf16(x_robot @ Wl0_rb); BB = 0; BB[dst] += inv_rb[dst]*BA[src]
    gemm_kernel<128, false, false, __hip_bfloat16><<<gblocks, 256, 0, stream>>>(NRB,
        x_robot, Wl0_rb, nullptr, nullptr, BA);
    hipMemsetAsync(BB, 0, NBIG * sizeof(float), stream);
    scatter128bf_kernel<<<sblocks128, 256, 0, stream>>>(BA, ei_rb, inv_rb, BB);
    // bl = relu(BB + x_ball @ Wr0_rb + b0_rb)  -> BB in place
    gemm_kernel<128, true, true, float><<<gblocks, 256, 0, stream>>>(NBL,
        x_ball, Wr0_rb, BB, b0_rb, BB);
    // z_br = bf16(bl @ Wl1_br)
    gemm_kernel<64, false, false, __hip_bfloat16><<<gblocks, 256, 0, stream>>>(NBL,
        BB, Wl1_br, nullptr, nullptr, z_br);

    // ---- robot path ----
    gemm_kernel<128, false, false, __hip_bfloat16><<<gblocks, 256, 0, stream>>>(NRB,
        x_robot, Wl0_rr, nullptr, nullptr, BA);
    hipMemsetAsync(BB, 0, NBIG * sizeof(float), stream);
    scatter128bf_kernel<<<sblocks128, 256, 0, stream>>>(BA, ei_rr, inv_rr, BB);
    gemm_kernel<128, false, false, __hip_bfloat16><<<gblocks, 256, 0, stream>>>(NBL,
        x_ball, Wl0_br, nullptr, nullptr, BA);
    scatter128bf_kernel<<<sblocks128, 256, 0, stream>>>(BA, ei_br, inv_br, BB);
    // r = relu(BB + x_robot @ (Wr0_rr+Wr0_br) + bsum0) -> BB in place
    gemm_kernel<128, true, true, float><<<gblocks, 256, 0, stream>>>(NRB,
        x_robot, Wsum0, BB, bsum0, BB);

    // ---- layer 1 ----
    // z_rr = bf16(r @ Wl1_rr)   (BA reused)
    gemm_kernel<64, false, false, __hip_bfloat16><<<gblocks, 256, 0, stream>>>(NRB,
        BB, Wl1_rr, nullptr, nullptr, z_rr);
    // out = r @ (Wr1_rr+Wr1_br) + (b1_rr+b1_br)
    gemm_kernel<64, false, false, float><<<gblocks, 256, 0, stream>>>(NRB,
        BB, Wsum1, nullptr, bsum1, (float*)d_out);
    // out[dst] += inv_rr[dst]*z_rr[src]  and  += inv_br[dst]*z_br[src]
    scatter64bf_kernel<<<sblocks64, 256, 0, stream>>>(z_rr, ei_rr, inv_rr, (float*)d_out);
    scatter64bf_kernel<<<sblocks64, 256, 0, stream>>>(z_br, ei_br, inv_br, (float*)d_out);
}

// Round 4
// 999.869 us; speedup vs baseline: 4.7480x; 4.7480x over previous
//
#include <hip/hip_runtime.h>
#include <hip/hip_bf16.h>
#include <cstddef>

#define NRB 100000      // robot nodes
#define NBL 100000      // ball nodes
#define NEDGE 600000    // edges per edge type
#define NSEG 300000     // concatenated dst space: [rr | rb | br], 100k each
// dims: 128 -> 128 -> 64
// NOTE: harness delivers integer inputs as int32 (edge indices are const int*).

// ---------------- CSR build ----------------

__global__ __launch_bounds__(256) void deg_kernel(const int* __restrict__ ei,
                                                  int* __restrict__ deg) {
    int e = blockIdx.x * 256 + threadIdx.x;
    if (e < NEDGE) atomicAdd(&deg[ei[NEDGE + e]], 1);
}

// exclusive scan over deg[NSEG] -> rowstart[NSEG+1]. 1024 elems/block.
__global__ __launch_bounds__(256) void scan1_kernel(const int* __restrict__ deg,
                                                    int* __restrict__ rowstart,
                                                    int* __restrict__ bsum) {
    __shared__ int sh[256];
    int t = threadIdx.x, blk = blockIdx.x;
    int base = blk * 1024 + t * 4;
    int v0 = (base + 0 < NSEG) ? deg[base + 0] : 0;
    int v1 = (base + 1 < NSEG) ? deg[base + 1] : 0;
    int v2 = (base + 2 < NSEG) ? deg[base + 2] : 0;
    int v3 = (base + 3 < NSEG) ? deg[base + 3] : 0;
    int tsum = v0 + v1 + v2 + v3;
    sh[t] = tsum; __syncthreads();
    for (int off = 1; off < 256; off <<= 1) {
        int x = (t >= off) ? sh[t - off] : 0;
        __syncthreads();
        sh[t] += x;
        __syncthreads();
    }
    int excl = sh[t] - tsum;
    if (t == 255) bsum[blk] = sh[255];
    if (base + 0 <= NSEG) rowstart[base + 0] = excl;
    if (base + 1 <= NSEG) rowstart[base + 1] = excl + v0;
    if (base + 2 <= NSEG) rowstart[base + 2] = excl + v0 + v1;
    if (base + 3 <= NSEG) rowstart[base + 3] = excl + v0 + v1 + v2;
}

__global__ __launch_bounds__(512) void scan2_kernel(int* __restrict__ bsum, int nb) {
    __shared__ int sh[512];
    int t = threadIdx.x;
    int v = (t < nb) ? bsum[t] : 0;
    sh[t] = v; __syncthreads();
    for (int off = 1; off < 512; off <<= 1) {
        int x = (t >= off) ? sh[t - off] : 0;
        __syncthreads();
        sh[t] += x;
        __syncthreads();
    }
    if (t < nb) bsum[t] = sh[t] - v;   // exclusive
}

__global__ __launch_bounds__(256) void scan3_kernel(int* __restrict__ rowstart,
                                                    const int* __restrict__ bsum) {
    int t = threadIdx.x, blk = blockIdx.x;
    int add = bsum[blk];
    int base = blk * 1024 + t * 4;
    #pragma unroll
    for (int j = 0; j < 4; ++j)
        if (base + j <= NSEG) rowstart[base + j] += add;
}

__global__ __launch_bounds__(256) void inv_kernel(const int* __restrict__ deg,
                                                  float* __restrict__ inv) {
    int i = blockIdx.x * 256 + threadIdx.x;
    if (i < NSEG) inv[i] = 1.0f / fmaxf((float)deg[i], 1.0f);
}

__global__ __launch_bounds__(256) void fill_kernel(const int* __restrict__ ei, int dstbase,
                                                   const int* __restrict__ rowstart,
                                                   int* __restrict__ cursor,
                                                   int* __restrict__ col) {
    int e = blockIdx.x * 256 + threadIdx.x;
    if (e >= NEDGE) return;
    int src = ei[e];
    int g = dstbase + ei[NEDGE + e];
    int pos = atomicAdd(&cursor[g], 1);
    col[rowstart[g] + pos] = src;
}

__global__ __launch_bounds__(256) void vecadd_kernel(const float* __restrict__ a,
                                                     const float* __restrict__ b,
                                                     float* __restrict__ c, int n) {
    int i = blockIdx.x * 256 + threadIdx.x;
    if (i < n) c[i] = a[i] + b[i];
}

// ---------------- gathers (no atomics) ----------------
// outbuf[row] (+)= inv[segbase+row] * sum_{j in CSR seg} y[col[j]]   (128-d bf16 rows)
// one wave per row; lane covers bf16x2 chunk (64 pairs = 128 elems).
template<bool ADD>
__global__ __launch_bounds__(256) void gather128_kernel(
    const __hip_bfloat16* __restrict__ y, const int* __restrict__ col,
    const int* __restrict__ rowstart, int segbase,
    const float* __restrict__ inv, float* __restrict__ outbuf, int nrows)
{
    int row = blockIdx.x * 4 + (threadIdx.x >> 6);
    if (row >= nrows) return;
    int lane = threadIdx.x & 63;
    int start = rowstart[segbase + row];
    int end   = rowstart[segbase + row + 1];
    const __hip_bfloat162* yb = (const __hip_bfloat162*)y;
    float2 acc = make_float2(0.f, 0.f);
    int j = start;
    for (; j + 1 < end; j += 2) {
        int s0 = col[j], s1 = col[j + 1];
        float2 a = __bfloat1622float2(yb[(size_t)s0 * 64 + lane]);
        float2 b = __bfloat1622float2(yb[(size_t)s1 * 64 + lane]);
        acc.x += a.x + b.x;
        acc.y += a.y + b.y;
    }
    if (j < end) {
        float2 a = __bfloat1622float2(yb[(size_t)col[j] * 64 + lane]);
        acc.x += a.x;
        acc.y += a.y;
    }
    float s = inv[segbase + row];
    float2* op = (float2*)(outbuf + (size_t)row * 128 + lane * 2);
    float2 r;
    if (ADD) {
        float2 cur = *op;
        r.x = cur.x + s * acc.x;
        r.y = cur.y + s * acc.y;
    } else {
        r.x = s * acc.x;
        r.y = s * acc.y;
    }
    *op = r;
}

// out[row] += inv_rr*sum z_rr[col] + inv_br*sum z_br[col]  (64-d bf16 rows)
// one wave per row; half-waves process alternating neighbors; xor-32 combine.
__global__ __launch_bounds__(256) void gather64_dual_kernel(
    const __hip_bfloat16* __restrict__ zrr, const __hip_bfloat16* __restrict__ zbr,
    const int* __restrict__ col, const int* __restrict__ rowstart,
    const float* __restrict__ inv, float* __restrict__ out)
{
    int row = blockIdx.x * 4 + (threadIdx.x >> 6);
    if (row >= NRB) return;
    int lane = threadIdx.x & 63;
    int half = lane >> 5, c = lane & 31;

    float2 accA = make_float2(0.f, 0.f);
    {
        int s = rowstart[row], e = rowstart[row + 1];
        const __hip_bfloat162* zb = (const __hip_bfloat162*)zrr;
        for (int j = s + half; j < e; j += 2) {
            float2 a = __bfloat1622float2(zb[(size_t)col[j] * 32 + c]);
            accA.x += a.x; accA.y += a.y;
        }
    }
    float2 accB = make_float2(0.f, 0.f);
    {
        int s = rowstart[200000 + row], e = rowstart[200000 + row + 1];
        const __hip_bfloat162* zb = (const __hip_bfloat162*)zbr;
        for (int j = s + half; j < e; j += 2) {
            float2 a = __bfloat1622float2(zb[(size_t)col[j] * 32 + c]);
            accB.x += a.x; accB.y += a.y;
        }
    }
    float ia = inv[row], ib = inv[200000 + row];
    float2 t;
    t.x = ia * accA.x + ib * accB.x;
    t.y = ia * accA.y + ib * accB.y;
    t.x += __shfl_xor(t.x, 32, 64);
    t.y += __shfl_xor(t.y, 32, 64);
    if (half == 0) {
        float2* op = (float2*)(out + (size_t)row * 64 + c * 2);
        float2 cur = *op;
        cur.x += t.x; cur.y += t.y;
        *op = cur;
    }
}

// ---------------- fused GEMM ----------------
// out[M,BN] = act( A @ W  (+ X0)  (+ bias) ), A is [M,128] fp32, W is [128,BN].
__device__ inline void store_out(float* p, float v) { *p = v; }
__device__ inline void store_out(__hip_bfloat16* p, float v) { *p = __float2bfloat16(v); }

template<int BN, bool WITH_X, bool RELU, typename OutT>
__global__ __launch_bounds__(256) void gemm_kernel(
    int M,
    const float* __restrict__ A, const float* __restrict__ W,
    const float* __restrict__ X0,
    const float* __restrict__ bias, OutT* __restrict__ out)
{
    const int TN = BN / 16;            // 8 (BN=128) or 4 (BN=64)
    __shared__ float As[16][68];
    __shared__ float Ws[16][BN];

    float acc[4][TN];
    #pragma unroll
    for (int i = 0; i < 4; ++i)
        #pragma unroll
        for (int j = 0; j < TN; ++j) acc[i][j] = 0.0f;

    const int row0 = blockIdx.x * 64;
    const int tid = threadIdx.x;
    const int tx = tid & 15;
    const int ty = tid >> 4;
    const int lm = tid >> 2;
    const int lc = tid & 3;
    const int gr = row0 + lm;

    for (int kb = 0; kb < 128; kb += 16) {
        float4 av = make_float4(0.f, 0.f, 0.f, 0.f);
        if (gr < M) av = *(const float4*)(A + (size_t)gr * 128 + kb + lc * 4);
        As[lc * 4 + 0][lm] = av.x;
        As[lc * 4 + 1][lm] = av.y;
        As[lc * 4 + 2][lm] = av.z;
        As[lc * 4 + 3][lm] = av.w;

        const int NL = (BN * 16) / (256 * 4);
        #pragma unroll
        for (int i = 0; i < NL; ++i) {
            int f = tid + i * 256;
            int k = f / (BN / 4);
            int c4 = f % (BN / 4);
            *(float4*)&Ws[k][c4 * 4] = *(const float4*)(W + (size_t)(kb + k) * BN + c4 * 4);
        }
        __syncthreads();

        #pragma unroll
        for (int k = 0; k < 16; ++k) {
            float4 a4 = *(const float4*)&As[k][ty * 4];
            float a[4] = {a4.x, a4.y, a4.z, a4.w};
            float b[TN];
            #pragma unroll
            for (int j = 0; j < TN; j += 4) {
                float4 b4 = *(const float4*)&Ws[k][tx * TN + j];
                b[j] = b4.x; b[j + 1] = b4.y; b[j + 2] = b4.z; b[j + 3] = b4.w;
            }
            #pragma unroll
            for (int i = 0; i < 4; ++i)
                #pragma unroll
                for (int j = 0; j < TN; ++j)
                    acc[i][j] += a[i] * b[j];
        }
        __syncthreads();
    }

    #pragma unroll
    for (int i = 0; i < 4; ++i) {
        int r = row0 + ty * 4 + i;
        if (r >= M) continue;
        #pragma unroll
        for (int j = 0; j < TN; ++j) {
            int col = tx * TN + j;
            float v = acc[i][j];
            if (WITH_X) v += X0[(size_t)r * BN + col];
            if (bias != nullptr) v += bias[col];
            if (RELU) v = fmaxf(v, 0.0f);
            store_out(&out[(size_t)r * BN + col], v);
        }
    }
}

// ---------------- launch ----------------
// Workspace (~102 MB):
//   BA  [12.8M] bf16 25.6 MB — y scratch (y_rb / y_rr / y_br), then z_rr
//   BB  [12.8M] fp32 51.2 MB — agg -> bl -> agg -> r (in place)
//   z_br [6.4M] bf16 12.8 MB
//   deg/cursor int 2×300k, rowstart int 300032, bsum 512, inv fp32 300k,
//   col_all int 1.8M (7.2 MB), weight sums ~0.1 MB

extern "C" void kernel_launch(void* const* d_in, const int* in_sizes, int n_in,
                              void* d_out, int out_size, void* d_ws, size_t ws_size,
                              hipStream_t stream) {
    (void)in_sizes; (void)n_in; (void)out_size; (void)ws_size;

    const float* x_robot = (const float*)d_in[0];
    const float* x_ball  = (const float*)d_in[1];
    const int* ei_rr = (const int*)d_in[2];   // [2, E] int32
    const int* ei_rb = (const int*)d_in[3];
    const int* ei_br = (const int*)d_in[4];
    const float* Wl0_rr = (const float*)d_in[5];
    const float* Wr0_rr = (const float*)d_in[6];
    const float* b0_rr  = (const float*)d_in[7];
    const float* Wl0_rb = (const float*)d_in[8];
    const float* Wr0_rb = (const float*)d_in[9];
    const float* b0_rb  = (const float*)d_in[10];
    const float* Wl0_br = (const float*)d_in[11];
    const float* Wr0_br = (const float*)d_in[12];
    const float* b0_br  = (const float*)d_in[13];
    const float* Wl1_rr = (const float*)d_in[14];
    const float* Wr1_rr = (const float*)d_in[15];
    const float* b1_rr  = (const float*)d_in[16];
    // d_in[17..19] unused (ball output not returned)
    const float* Wl1_br = (const float*)d_in[20];
    const float* Wr1_br = (const float*)d_in[21];
    const float* b1_br  = (const float*)d_in[22];

    const size_t NBIG = (size_t)NRB * 128;
    __hip_bfloat16* BA = (__hip_bfloat16*)d_ws;              // NBIG bf16
    float* BB = (float*)(BA + NBIG);                          // NBIG fp32
    __hip_bfloat16* z_br = (__hip_bfloat16*)(BB + NBIG);      // NBL*64 bf16
    int* deg      = (int*)(z_br + (size_t)NBL * 64);          // NSEG
    int* cursor   = deg + NSEG;                               // NSEG (contiguous w/ deg for one memset)
    int* rowstart = cursor + NSEG;                            // NSEG+32
    int* bsum     = rowstart + NSEG + 32;                     // 512
    float* inv    = (float*)(bsum + 512);                     // NSEG
    int* col_all  = (int*)(inv + NSEG);                       // 3*NEDGE
    float* Wsum0  = (float*)(col_all + 3 * NEDGE);            // 128x128
    float* bsum0  = Wsum0 + 128 * 128;
    float* Wsum1  = bsum0 + 128;                              // 128x64
    float* bsum1  = Wsum1 + 128 * 64;
    __hip_bfloat16* z_rr = BA;                                // reuse after y dead

    const int SCAN_BLOCKS = (NSEG + 1024) / 1024;             // 293

    // ---- CSR build ----
    hipMemsetAsync(deg, 0, 2 * NSEG * sizeof(int), stream);   // deg + cursor
    const int eblocks = (NEDGE + 255) / 256;
    deg_kernel<<<eblocks, 256, 0, stream>>>(ei_rr, deg);
    deg_kernel<<<eblocks, 256, 0, stream>>>(ei_rb, deg + 100000);
    deg_kernel<<<eblocks, 256, 0, stream>>>(ei_br, deg + 200000);
    scan1_kernel<<<SCAN_BLOCKS, 256, 0, stream>>>(deg, rowstart, bsum);
    scan2_kernel<<<1, 512, 0, stream>>>(bsum, SCAN_BLOCKS);
    scan3_kernel<<<SCAN_BLOCKS, 256, 0, stream>>>(rowstart, bsum);
    inv_kernel<<<(NSEG + 255) / 256, 256, 0, stream>>>(deg, inv);
    fill_kernel<<<eblocks, 256, 0, stream>>>(ei_rr, 0,      rowstart, cursor, col_all);
    fill_kernel<<<eblocks, 256, 0, stream>>>(ei_rb, 100000, rowstart, cursor, col_all);
    fill_kernel<<<eblocks, 256, 0, stream>>>(ei_br, 200000, rowstart, cursor, col_all);

    // ---- weight sums (HeteroConv aggr='sum' folds robot-dst self terms) ----
    vecadd_kernel<<<(16384 + 255) / 256, 256, 0, stream>>>(Wr0_rr, Wr0_br, Wsum0, 16384);
    vecadd_kernel<<<1, 256, 0, stream>>>(b0_rr, b0_br, bsum0, 128);
    vecadd_kernel<<<(8192 + 255) / 256, 256, 0, stream>>>(Wr1_rr, Wr1_br, Wsum1, 8192);
    vecadd_kernel<<<1, 256, 0, stream>>>(b1_rr, b1_br, bsum1, 64);

    const int gblocks = (NRB + 63) / 64;
    const int rblocks = (NRB + 3) / 4;   // gather: 4 rows/block

    // ---- ball path ----
    gemm_kernel<128, false, false, __hip_bfloat16><<<gblocks, 256, 0, stream>>>(NRB,
        x_robot, Wl0_rb, nullptr, nullptr, BA);                        // y_rb
    gather128_kernel<false><<<rblocks, 256, 0, stream>>>(BA, col_all, rowstart, 100000,
        inv, BB, NBL);                                                  // mean msgs -> BB
    gemm_kernel<128, true, true, float><<<gblocks, 256, 0, stream>>>(NBL,
        x_ball, Wr0_rb, BB, b0_rb, BB);                                 // bl (in place)
    gemm_kernel<64, false, false, __hip_bfloat16><<<gblocks, 256, 0, stream>>>(NBL,
        BB, Wl1_br, nullptr, nullptr, z_br);                            // z_br

    // ---- robot path ----
    gemm_kernel<128, false, false, __hip_bfloat16><<<gblocks, 256, 0, stream>>>(NRB,
        x_robot, Wl0_rr, nullptr, nullptr, BA);                        // y_rr
    gather128_kernel<false><<<rblocks, 256, 0, stream>>>(BA, col_all, rowstart, 0,
        inv, BB, NRB);
    gemm_kernel<128, false, false, __hip_bfloat16><<<gblocks, 256, 0, stream>>>(NBL,
        x_ball, Wl0_br, nullptr, nullptr, BA);                         // y_br
    gather128_kernel<true><<<rblocks, 256, 0, stream>>>(BA, col_all, rowstart, 200000,
        inv, BB, NRB);
    gemm_kernel<128, true, true, float><<<gblocks, 256, 0, stream>>>(NRB,
        x_robot, Wsum0, BB, bsum0, BB);                                 // r (in place)

    // ---- layer 1 ----
    gemm_kernel<64, false, false, __hip_bfloat16><<<gblocks, 256, 0, stream>>>(NRB,
        BB, Wl1_rr, nullptr, nullptr, z_rr);                            // z_rr (BA reuse)
    gemm_kernel<64, false, false, float><<<gblocks, 256, 0, stream>>>(NRB,
        BB, Wsum1, nullptr, bsum1, (float*)d_out);                      // self term + bias
    gather64_dual_kernel<<<rblocks, 256, 0, stream>>>(z_rr, z_br, col_all, rowstart,
        inv, (float*)d_out);                                            // += both aggregations
}

// Round 5
// 783.246 us; speedup vs baseline: 6.0611x; 1.2766x over previous
//
#include <hip/hip_runtime.h>
#include <hip/hip_bf16.h>
#include <cstddef>

#define NRB 100000      // robot nodes
#define NBL 100000      // ball nodes
#define NEDGE 600000    // edges per edge type
#define NSEG 300000     // concatenated dst space: [rr | rb | br], 100k each
// dims: 128 -> 128 -> 64
// NOTE: harness delivers integer inputs as int32 (edge indices are const int*).

typedef __attribute__((ext_vector_type(8))) short short8;
typedef __attribute__((ext_vector_type(4))) float floatx4;

// ---------------- CSR build ----------------

__global__ __launch_bounds__(256) void deg_kernel(const int* __restrict__ ei,
                                                  int* __restrict__ deg) {
    int e = blockIdx.x * 256 + threadIdx.x;
    if (e < NEDGE) atomicAdd(&deg[ei[NEDGE + e]], 1);
}

__global__ __launch_bounds__(256) void scan1_kernel(const int* __restrict__ deg,
                                                    int* __restrict__ rowstart,
                                                    int* __restrict__ bsum) {
    __shared__ int sh[256];
    int t = threadIdx.x, blk = blockIdx.x;
    int base = blk * 1024 + t * 4;
    int v0 = (base + 0 < NSEG) ? deg[base + 0] : 0;
    int v1 = (base + 1 < NSEG) ? deg[base + 1] : 0;
    int v2 = (base + 2 < NSEG) ? deg[base + 2] : 0;
    int v3 = (base + 3 < NSEG) ? deg[base + 3] : 0;
    int tsum = v0 + v1 + v2 + v3;
    sh[t] = tsum; __syncthreads();
    for (int off = 1; off < 256; off <<= 1) {
        int x = (t >= off) ? sh[t - off] : 0;
        __syncthreads();
        sh[t] += x;
        __syncthreads();
    }
    int excl = sh[t] - tsum;
    if (t == 255) bsum[blk] = sh[255];
    if (base + 0 <= NSEG) rowstart[base + 0] = excl;
    if (base + 1 <= NSEG) rowstart[base + 1] = excl + v0;
    if (base + 2 <= NSEG) rowstart[base + 2] = excl + v0 + v1;
    if (base + 3 <= NSEG) rowstart[base + 3] = excl + v0 + v1 + v2;
}

__global__ __launch_bounds__(512) void scan2_kernel(int* __restrict__ bsum, int nb) {
    __shared__ int sh[512];
    int t = threadIdx.x;
    int v = (t < nb) ? bsum[t] : 0;
    sh[t] = v; __syncthreads();
    for (int off = 1; off < 512; off <<= 1) {
        int x = (t >= off) ? sh[t - off] : 0;
        __syncthreads();
        sh[t] += x;
        __syncthreads();
    }
    if (t < nb) bsum[t] = sh[t] - v;   // exclusive
}

__global__ __launch_bounds__(256) void scan3_kernel(int* __restrict__ rowstart,
                                                    const int* __restrict__ bsum) {
    int t = threadIdx.x, blk = blockIdx.x;
    int add = bsum[blk];
    int base = blk * 1024 + t * 4;
    #pragma unroll
    for (int j = 0; j < 4; ++j)
        if (base + j <= NSEG) rowstart[base + j] += add;
}

__global__ __launch_bounds__(256) void inv_kernel(const int* __restrict__ deg,
                                                  float* __restrict__ inv) {
    int i = blockIdx.x * 256 + threadIdx.x;
    if (i < NSEG) inv[i] = 1.0f / fmaxf((float)deg[i], 1.0f);
}

__global__ __launch_bounds__(256) void fill_kernel(const int* __restrict__ ei, int dstbase,
                                                   const int* __restrict__ rowstart,
                                                   int* __restrict__ cursor,
                                                   int* __restrict__ col) {
    int e = blockIdx.x * 256 + threadIdx.x;
    if (e >= NEDGE) return;
    int src = ei[e];
    int g = dstbase + ei[NEDGE + e];
    int pos = atomicAdd(&cursor[g], 1);
    col[rowstart[g] + pos] = src;
}

__global__ __launch_bounds__(256) void vecadd_kernel(const float* __restrict__ a,
                                                     const float* __restrict__ b,
                                                     float* __restrict__ c, int n) {
    int i = blockIdx.x * 256 + threadIdx.x;
    if (i < n) c[i] = a[i] + b[i];
}

// transpose+convert weights: dst[n][k] = bf16(A[k][n] (+ B[k][n])), A is [128][dout] fp32
__global__ __launch_bounds__(256) void wprep_kernel(const float* __restrict__ A,
                                                    const float* __restrict__ B,
                                                    __hip_bfloat16* __restrict__ dst, int dout) {
    int t = blockIdx.x * 256 + threadIdx.x;
    if (t >= dout * 128) return;
    int k = t & 127, n = t >> 7;
    float v = A[k * dout + n];
    if (B != nullptr) v += B[k * dout + n];
    dst[n * 128 + k] = __float2bfloat16(v);
}

// ---------------- MFMA GEMM ----------------
// C[M, BN] = A[M,128] @ W_slice^T, slices selected by blockIdx.y from WT (concatenated [n][k] bf16).
// Block tile 128 x BN, 4 waves (2x2), wave tile 64 x (BN/2), 16x16x32 bf16 MFMA, K=128 fully in LDS.
template<int BN, bool AF32>
__global__ __launch_bounds__(256) void mfma_gemm_kernel(
    int M, const void* __restrict__ Av,
    const __hip_bfloat16* __restrict__ WT,
    void* __restrict__ o0, void* __restrict__ o1, void* __restrict__ o2,
    const float* __restrict__ bias0, const float* __restrict__ bias1, const float* __restrict__ bias2,
    int f32mask)
{
    constexpr int NT = BN / 32;              // n-tiles per wave: 4 (BN=128) or 2 (BN=64)
    __shared__ __hip_bfloat16 As[128][136];  // pad 8 bf16 -> 2-way bank alias (free)
    __shared__ __hip_bfloat16 Bs[BN][136];

    const int tid = threadIdx.x;
    const int bm = blockIdx.x, by = blockIdx.y;
    const int c = tid & 15;        // 8-elem chunk within row
    const int rbase = tid >> 4;    // 0..15

    // ---- stage A (convert fp32->bf16 if needed) ----
    if (AF32) {
        const float* A = (const float*)Av;
        #pragma unroll
        for (int p = 0; p < 8; ++p) {
            int r = p * 16 + rbase;
            int gr = bm * 128 + r;
            float4 u = make_float4(0.f, 0.f, 0.f, 0.f), v = make_float4(0.f, 0.f, 0.f, 0.f);
            if (gr < M) {
                const float* src = A + (size_t)gr * 128 + c * 8;
                u = *(const float4*)(src);
                v = *(const float4*)(src + 4);
            }
            __hip_bfloat16* d = &As[r][c * 8];
            d[0] = __float2bfloat16(u.x); d[1] = __float2bfloat16(u.y);
            d[2] = __float2bfloat16(u.z); d[3] = __float2bfloat16(u.w);
            d[4] = __float2bfloat16(v.x); d[5] = __float2bfloat16(v.y);
            d[6] = __float2bfloat16(v.z); d[7] = __float2bfloat16(v.w);
        }
    } else {
        const __hip_bfloat16* A = (const __hip_bfloat16*)Av;
        #pragma unroll
        for (int p = 0; p < 8; ++p) {
            int r = p * 16 + rbase;
            int gr = bm * 128 + r;
            int4 u = make_int4(0, 0, 0, 0);
            if (gr < M) u = *(const int4*)(A + (size_t)gr * 128 + c * 8);
            *(int4*)&As[r][c * 8] = u;
        }
    }
    // ---- stage B (bf16 WT rows, contiguous) ----
    {
        const __hip_bfloat16* Wb = WT + (size_t)by * BN * 128;
        #pragma unroll
        for (int p = 0; p < BN / 16; ++p) {
            int r = p * 16 + rbase;
            *(int4*)&Bs[r][c * 8] = *(const int4*)(Wb + (size_t)r * 128 + c * 8);
        }
    }
    __syncthreads();

    const int wave = tid >> 6, lane = tid & 63;
    const int wm = wave >> 1, wn = wave & 1;
    const int lrow = lane & 15, lquad = lane >> 4;

    floatx4 acc[4][NT];
    #pragma unroll
    for (int mt = 0; mt < 4; ++mt)
        #pragma unroll
        for (int nt = 0; nt < NT; ++nt)
            acc[mt][nt] = (floatx4){0.f, 0.f, 0.f, 0.f};

    #pragma unroll
    for (int ks = 0; ks < 4; ++ks) {
        short8 af[4], bf[NT];
        #pragma unroll
        for (int mt = 0; mt < 4; ++mt)
            af[mt] = *(const short8*)&As[wm * 64 + mt * 16 + lrow][ks * 32 + lquad * 8];
        #pragma unroll
        for (int nt = 0; nt < NT; ++nt)
            bf[nt] = *(const short8*)&Bs[wn * (BN / 2) + nt * 16 + lrow][ks * 32 + lquad * 8];
        #pragma unroll
        for (int mt = 0; mt < 4; ++mt)
            #pragma unroll
            for (int nt = 0; nt < NT; ++nt)
                acc[mt][nt] = __builtin_amdgcn_mfma_f32_16x16x32_bf16(af[mt], bf[nt], acc[mt][nt], 0, 0, 0);
    }

    // ---- epilogue: per-slice out pointer / bias / dtype ----
    void* op = (by == 0) ? o0 : ((by == 1) ? o1 : o2);
    const float* bp = (by == 0) ? bias0 : ((by == 1) ? bias1 : bias2);
    const bool isf = (f32mask >> by) & 1;
    #pragma unroll
    for (int mt = 0; mt < 4; ++mt) {
        #pragma unroll
        for (int nt = 0; nt < NT; ++nt) {
            int gcol = wn * (BN / 2) + nt * 16 + lrow;
            float bv = (bp != nullptr) ? bp[gcol] : 0.0f;
            #pragma unroll
            for (int r4 = 0; r4 < 4; ++r4) {
                int grow = bm * 128 + wm * 64 + mt * 16 + lquad * 4 + r4;
                if (grow < M) {
                    float v = acc[mt][nt][r4] + bv;   // C/D: col=lane&15, row=quad*4+reg (m89)
                    if (isf) ((float*)op)[(size_t)grow * BN + gcol] = v;
                    else ((__hip_bfloat16*)op)[(size_t)grow * BN + gcol] = __float2bfloat16(v);
                }
            }
        }
    }
}

// ---------------- gathers (no atomics, fused epilogues) ----------------
// r[row] = relu(inv_rr*sum y_rr[col] + inv_br*sum y_br[col] + sr[row])  -> bf16
__global__ __launch_bounds__(256) void gather_r_kernel(
    const __hip_bfloat16* __restrict__ y_rr, const __hip_bfloat16* __restrict__ y_br,
    const __hip_bfloat16* __restrict__ sr,
    const int* __restrict__ col, const int* __restrict__ rowstart,
    const float* __restrict__ inv, __hip_bfloat16* __restrict__ r_out)
{
    int row = blockIdx.x * 4 + (threadIdx.x >> 6);
    if (row >= NRB) return;
    int lane = threadIdx.x & 63;
    float2 a = make_float2(0.f, 0.f);
    {
        int s = rowstart[row], e = rowstart[row + 1];
        const __hip_bfloat162* yb = (const __hip_bfloat162*)y_rr;
        int j = s;
        for (; j + 1 < e; j += 2) {
            float2 u = __bfloat1622float2(yb[(size_t)col[j] * 64 + lane]);
            float2 v = __bfloat1622float2(yb[(size_t)col[j + 1] * 64 + lane]);
            a.x += u.x + v.x; a.y += u.y + v.y;
        }
        if (j < e) {
            float2 u = __bfloat1622float2(yb[(size_t)col[j] * 64 + lane]);
            a.x += u.x; a.y += u.y;
        }
    }
    float2 b = make_float2(0.f, 0.f);
    {
        int s = rowstart[200000 + row], e = rowstart[200000 + row + 1];
        const __hip_bfloat162* yb = (const __hip_bfloat162*)y_br;
        int j = s;
        for (; j + 1 < e; j += 2) {
            float2 u = __bfloat1622float2(yb[(size_t)col[j] * 64 + lane]);
            float2 v = __bfloat1622float2(yb[(size_t)col[j + 1] * 64 + lane]);
            b.x += u.x + v.x; b.y += u.y + v.y;
        }
        if (j < e) {
            float2 u = __bfloat1622float2(yb[(size_t)col[j] * 64 + lane]);
            b.x += u.x; b.y += u.y;
        }
    }
    float ia = inv[row], ib = inv[200000 + row];
    float2 s2 = __bfloat1622float2(((const __hip_bfloat162*)sr)[(size_t)row * 64 + lane]);
    float vx = fmaxf(ia * a.x + ib * b.x + s2.x, 0.f);
    float vy = fmaxf(ia * a.y + ib * b.y + s2.y, 0.f);
    __hip_bfloat162 h;
    h.x = __float2bfloat16(vx); h.y = __float2bfloat16(vy);
    ((__hip_bfloat162*)r_out)[(size_t)row * 64 + lane] = h;
}

// bl[row] = relu(inv_rb*sum y_rb[col] + sb[row]) -> bf16
__global__ __launch_bounds__(256) void gather_bl_kernel(
    const __hip_bfloat16* __restrict__ y_rb, const __hip_bfloat16* __restrict__ sb,
    const int* __restrict__ col, const int* __restrict__ rowstart,
    const float* __restrict__ inv, __hip_bfloat16* __restrict__ bl_out)
{
    int row = blockIdx.x * 4 + (threadIdx.x >> 6);
    if (row >= NBL) return;
    int lane = threadIdx.x & 63;
    float2 a = make_float2(0.f, 0.f);
    int s = rowstart[100000 + row], e = rowstart[100000 + row + 1];
    const __hip_bfloat162* yb = (const __hip_bfloat162*)y_rb;
    int j = s;
    for (; j + 1 < e; j += 2) {
        float2 u = __bfloat1622float2(yb[(size_t)col[j] * 64 + lane]);
        float2 v = __bfloat1622float2(yb[(size_t)col[j + 1] * 64 + lane]);
        a.x += u.x + v.x; a.y += u.y + v.y;
    }
    if (j < e) {
        float2 u = __bfloat1622float2(yb[(size_t)col[j] * 64 + lane]);
        a.x += u.x; a.y += u.y;
    }
    float ia = inv[100000 + row];
    float2 s2 = __bfloat1622float2(((const __hip_bfloat162*)sb)[(size_t)row * 64 + lane]);
    __hip_bfloat162 h;
    h.x = __float2bfloat16(fmaxf(ia * a.x + s2.x, 0.f));
    h.y = __float2bfloat16(fmaxf(ia * a.y + s2.y, 0.f));
    ((__hip_bfloat162*)bl_out)[(size_t)row * 64 + lane] = h;
}

// out[row] += inv_rr*sum z_rr[col] + inv_br*sum z_br[col]  (64-d bf16 -> fp32 d_out)
__global__ __launch_bounds__(256) void gather64_dual_kernel(
    const __hip_bfloat16* __restrict__ zrr, const __hip_bfloat16* __restrict__ zbr,
    const int* __restrict__ col, const int* __restrict__ rowstart,
    const float* __restrict__ inv, float* __restrict__ out)
{
    int row = blockIdx.x * 4 + (threadIdx.x >> 6);
    if (row >= NRB) return;
    int lane = threadIdx.x & 63;
    int half = lane >> 5, c = lane & 31;

    float2 accA = make_float2(0.f, 0.f);
    {
        int s = rowstart[row], e = rowstart[row + 1];
        const __hip_bfloat162* zb = (const __hip_bfloat162*)zrr;
        for (int j = s + half; j < e; j += 2) {
            float2 a = __bfloat1622float2(zb[(size_t)col[j] * 32 + c]);
            accA.x += a.x; accA.y += a.y;
        }
    }
    float2 accB = make_float2(0.f, 0.f);
    {
        int s = rowstart[200000 + row], e = rowstart[200000 + row + 1];
        const __hip_bfloat162* zb = (const __hip_bfloat162*)zbr;
        for (int j = s + half; j < e; j += 2) {
            float2 a = __bfloat1622float2(zb[(size_t)col[j] * 32 + c]);
            accB.x += a.x; accB.y += a.y;
        }
    }
    float ia = inv[row], ib = inv[200000 + row];
    float2 t;
    t.x = ia * accA.x + ib * accB.x;
    t.y = ia * accA.y + ib * accB.y;
    t.x += __shfl_xor(t.x, 32, 64);
    t.y += __shfl_xor(t.y, 32, 64);
    if (half == 0) {
        float2* op = (float2*)(out + (size_t)row * 64 + c * 2);
        float2 cur = *op;
        cur.x += t.x; cur.y += t.y;
        *op = cur;
    }
}

// ---------------- launch ----------------
// Workspace (~166 MB): 6 bf16 slots of 25.6 MB + WT 0.21 MB + CSR ~12 MB + biases.

extern "C" void kernel_launch(void* const* d_in, const int* in_sizes, int n_in,
                              void* d_out, int out_size, void* d_ws, size_t ws_size,
                              hipStream_t stream) {
    (void)in_sizes; (void)n_in; (void)out_size; (void)ws_size;

    const float* x_robot = (const float*)d_in[0];
    const float* x_ball  = (const float*)d_in[1];
    const int* ei_rr = (const int*)d_in[2];   // [2, E] int32
    const int* ei_rb = (const int*)d_in[3];
    const int* ei_br = (const int*)d_in[4];
    const float* Wl0_rr = (const float*)d_in[5];
    const float* Wr0_rr = (const float*)d_in[6];
    const float* b0_rr  = (const float*)d_in[7];
    const float* Wl0_rb = (const float*)d_in[8];
    const float* Wr0_rb = (const float*)d_in[9];
    const float* b0_rb  = (const float*)d_in[10];
    const float* Wl0_br = (const float*)d_in[11];
    const float* Wr0_br = (const float*)d_in[12];
    const float* b0_br  = (const float*)d_in[13];
    const float* Wl1_rr = (const float*)d_in[14];
    const float* Wr1_rr = (const float*)d_in[15];
    const float* b1_rr  = (const float*)d_in[16];
    // d_in[17..19] unused (ball output not returned)
    const float* Wl1_br = (const float*)d_in[20];
    const float* Wr1_br = (const float*)d_in[21];
    const float* b1_br  = (const float*)d_in[22];

    const size_t NBIG = (size_t)NRB * 128;   // elems per slot
    __hip_bfloat16* S0 = (__hip_bfloat16*)d_ws;    // y_rb, later z_br
    __hip_bfloat16* S1 = S0 + NBIG;                // y_rr, later z_rr
    __hip_bfloat16* S2 = S1 + NBIG;                // y_br
    __hip_bfloat16* S3 = S2 + NBIG;                // sr, later bl
    __hip_bfloat16* S4 = S3 + NBIG;                // sb
    __hip_bfloat16* S5 = S4 + NBIG;                // r
    __hip_bfloat16* WT1 = S5 + NBIG;               // 384*128
    __hip_bfloat16* WT2 = WT1 + 384 * 128;         // 256*128
    __hip_bfloat16* WT3 = WT2 + 256 * 128;         // 64*128
    __hip_bfloat16* WT4 = WT3 + 64 * 128;          // 128*128
    int* col_all  = (int*)(WT4 + 128 * 128);       // 3*NEDGE
    int* deg      = col_all + 3 * NEDGE;           // NSEG
    int* cursor   = deg + NSEG;                    // NSEG (adjacent for one memset)
    int* rowstart = cursor + NSEG;                 // NSEG+32
    int* bsum     = rowstart + NSEG + 32;          // 512
    float* inv    = (float*)(bsum + 512);          // NSEG
    float* bsum0  = inv + NSEG;                    // 128
    float* bsum1  = bsum0 + 128;                   // 64

    __hip_bfloat16* y_rb = S0; __hip_bfloat16* z_br = S0;
    __hip_bfloat16* y_rr = S1; __hip_bfloat16* z_rr = S1;
    __hip_bfloat16* y_br = S2;
    __hip_bfloat16* sr = S3;   __hip_bfloat16* bl = S3;
    __hip_bfloat16* sb = S4;
    __hip_bfloat16* r  = S5;

    const int SCAN_BLOCKS = (NSEG + 1024) / 1024;

    // ---- CSR build ----
    hipMemsetAsync(deg, 0, 2 * NSEG * sizeof(int), stream);
    const int eblocks = (NEDGE + 255) / 256;
    deg_kernel<<<eblocks, 256, 0, stream>>>(ei_rr, deg);
    deg_kernel<<<eblocks, 256, 0, stream>>>(ei_rb, deg + 100000);
    deg_kernel<<<eblocks, 256, 0, stream>>>(ei_br, deg + 200000);
    scan1_kernel<<<SCAN_BLOCKS, 256, 0, stream>>>(deg, rowstart, bsum);
    scan2_kernel<<<1, 512, 0, stream>>>(bsum, SCAN_BLOCKS);
    scan3_kernel<<<SCAN_BLOCKS, 256, 0, stream>>>(rowstart, bsum);
    inv_kernel<<<(NSEG + 255) / 256, 256, 0, stream>>>(deg, inv);
    fill_kernel<<<eblocks, 256, 0, stream>>>(ei_rr, 0,      rowstart, cursor, col_all);
    fill_kernel<<<eblocks, 256, 0, stream>>>(ei_rb, 100000, rowstart, cursor, col_all);
    fill_kernel<<<eblocks, 256, 0, stream>>>(ei_br, 200000, rowstart, cursor, col_all);

    // ---- weight prep: WT[n][k] bf16, fused sums ----
    vecadd_kernel<<<1, 256, 0, stream>>>(b0_rr, b0_br, bsum0, 128);
    vecadd_kernel<<<1, 256, 0, stream>>>(b1_rr, b1_br, bsum1, 64);
    wprep_kernel<<<64, 256, 0, stream>>>(Wl0_rb, nullptr, WT1 + 0 * 128 * 128, 128);
    wprep_kernel<<<64, 256, 0, stream>>>(Wl0_rr, nullptr, WT1 + 1 * 128 * 128, 128);
    wprep_kernel<<<64, 256, 0, stream>>>(Wr0_rr, Wr0_br,  WT1 + 2 * 128 * 128, 128);
    wprep_kernel<<<64, 256, 0, stream>>>(Wl0_br, nullptr, WT2 + 0 * 128 * 128, 128);
    wprep_kernel<<<64, 256, 0, stream>>>(Wr0_rb, nullptr, WT2 + 1 * 128 * 128, 128);
    wprep_kernel<<<32, 256, 0, stream>>>(Wl1_br, nullptr, WT3, 64);
    wprep_kernel<<<32, 256, 0, stream>>>(Wl1_rr, nullptr, WT4 + 0 * 64 * 128, 64);
    wprep_kernel<<<32, 256, 0, stream>>>(Wr1_rr, Wr1_br,  WT4 + 1 * 64 * 128, 64);

    const int gm = (NRB + 127) / 128;          // 782
    const int rblocks = (NRB + 3) / 4;         // gathers: 4 rows/block

    // GEMM1: x_robot @ [Wl0_rb | Wl0_rr | Wsum0(+bsum0)] -> y_rb, y_rr, sr (all bf16)
    mfma_gemm_kernel<128, true><<<dim3(gm, 3), 256, 0, stream>>>(NRB,
        x_robot, WT1, y_rb, y_rr, sr, nullptr, nullptr, bsum0, 0);
    // GEMM2: x_ball @ [Wl0_br | Wr0_rb(+b0_rb)] -> y_br, sb (bf16)
    mfma_gemm_kernel<128, true><<<dim3(gm, 2), 256, 0, stream>>>(NBL,
        x_ball, WT2, y_br, sb, nullptr, nullptr, b0_rb, nullptr, 0);
    // r = relu(mean_rr(y_rr) + mean_br(y_br) + sr)
    gather_r_kernel<<<rblocks, 256, 0, stream>>>(y_rr, y_br, sr, col_all, rowstart, inv, r);
    // GEMM4: r @ [Wl1_rr | Wsum1(+bsum1)] -> z_rr (bf16), d_out self term (fp32)
    mfma_gemm_kernel<64, false><<<dim3(gm, 2), 256, 0, stream>>>(NRB,
        r, WT4, z_rr, d_out, nullptr, nullptr, bsum1, nullptr, 2);
    // bl = relu(mean_rb(y_rb) + sb)
    gather_bl_kernel<<<rblocks, 256, 0, stream>>>(y_rb, sb, col_all, rowstart, inv, bl);
    // GEMM3: bl @ Wl1_br -> z_br (bf16)
    mfma_gemm_kernel<64, false><<<dim3(gm, 1), 256, 0, stream>>>(NBL,
        bl, WT3, z_br, nullptr, nullptr, nullptr, nullptr, nullptr, 0);
    // out += mean_rr(z_rr) + mean_br(z_br)
    gather64_dual_kernel<<<rblocks, 256, 0, stream>>>(z_rr, z_br, col_all, rowstart,
        inv, (float*)d_out);
}

// Round 6
// 773.843 us; speedup vs baseline: 6.1347x; 1.0122x over previous
//
#include <hip/hip_runtime.h>
#include <hip/hip_bf16.h>
#include <cstddef>

#define NRB 100000      // robot nodes
#define NBL 100000      // ball nodes
#define NEDGE 600000    // edges per edge type
#define NSEG 300000     // concatenated dst space: [rr | rb | br], 100k each
// dims: 128 -> 128 -> 64
// NOTE: harness delivers integer inputs as int32 (edge indices are const int*).

typedef __attribute__((ext_vector_type(8))) short short8;
typedef __attribute__((ext_vector_type(4))) float floatx4;

// ---------------- CSR build (merged) ----------------

__global__ __launch_bounds__(256) void deg_all_kernel(const int* __restrict__ ei0,
                                                      const int* __restrict__ ei1,
                                                      const int* __restrict__ ei2,
                                                      int* __restrict__ deg) {
    int e = blockIdx.x * 256 + threadIdx.x;
    if (e >= NEDGE) return;
    const int* ei = (blockIdx.y == 0) ? ei0 : ((blockIdx.y == 1) ? ei1 : ei2);
    atomicAdd(&deg[blockIdx.y * 100000 + ei[NEDGE + e]], 1);
}

__global__ __launch_bounds__(256) void scan1_kernel(const int* __restrict__ deg,
                                                    int* __restrict__ rowstart,
                                                    int* __restrict__ bsum) {
    __shared__ int sh[256];
    int t = threadIdx.x, blk = blockIdx.x;
    int base = blk * 1024 + t * 4;
    int v0 = (base + 0 < NSEG) ? deg[base + 0] : 0;
    int v1 = (base + 1 < NSEG) ? deg[base + 1] : 0;
    int v2 = (base + 2 < NSEG) ? deg[base + 2] : 0;
    int v3 = (base + 3 < NSEG) ? deg[base + 3] : 0;
    int tsum = v0 + v1 + v2 + v3;
    sh[t] = tsum; __syncthreads();
    for (int off = 1; off < 256; off <<= 1) {
        int x = (t >= off) ? sh[t - off] : 0;
        __syncthreads();
        sh[t] += x;
        __syncthreads();
    }
    int excl = sh[t] - tsum;
    if (t == 255) bsum[blk] = sh[255];
    if (base + 0 <= NSEG) rowstart[base + 0] = excl;
    if (base + 1 <= NSEG) rowstart[base + 1] = excl + v0;
    if (base + 2 <= NSEG) rowstart[base + 2] = excl + v0 + v1;
    if (base + 3 <= NSEG) rowstart[base + 3] = excl + v0 + v1 + v2;
}

__global__ __launch_bounds__(512) void scan2_kernel(int* __restrict__ bsum, int nb) {
    __shared__ int sh[512];
    int t = threadIdx.x;
    int v = (t < nb) ? bsum[t] : 0;
    sh[t] = v; __syncthreads();
    for (int off = 1; off < 512; off <<= 1) {
        int x = (t >= off) ? sh[t - off] : 0;
        __syncthreads();
        sh[t] += x;
        __syncthreads();
    }
    if (t < nb) bsum[t] = sh[t] - v;   // exclusive
}

// scan3 + inv fused
__global__ __launch_bounds__(256) void scan3_inv_kernel(int* __restrict__ rowstart,
                                                        const int* __restrict__ bsum,
                                                        const int* __restrict__ deg,
                                                        float* __restrict__ inv) {
    int t = threadIdx.x, blk = blockIdx.x;
    int add = bsum[blk];
    int base = blk * 1024 + t * 4;
    #pragma unroll
    for (int j = 0; j < 4; ++j) {
        if (base + j <= NSEG) rowstart[base + j] += add;
        if (base + j < NSEG) inv[base + j] = 1.0f / fmaxf((float)deg[base + j], 1.0f);
    }
}

__global__ __launch_bounds__(256) void fill_all_kernel(const int* __restrict__ ei0,
                                                       const int* __restrict__ ei1,
                                                       const int* __restrict__ ei2,
                                                       const int* __restrict__ rowstart,
                                                       int* __restrict__ cursor,
                                                       int* __restrict__ col) {
    int e = blockIdx.x * 256 + threadIdx.x;
    if (e >= NEDGE) return;
    const int* ei = (blockIdx.y == 0) ? ei0 : ((blockIdx.y == 1) ? ei1 : ei2);
    int src = ei[e];
    int g = blockIdx.y * 100000 + ei[NEDGE + e];
    int pos = atomicAdd(&cursor[g], 1);
    col[rowstart[g] + pos] = src;
}

// ---------------- weight prep (all jobs in one launch) ----------------
// WT[n][k] = bf16(W[k][n] (+ W2[k][n])); job 8 does both bias sums.
__global__ __launch_bounds__(256) void wprep_all_kernel(
    const float* Wl0_rb, const float* Wl0_rr, const float* Wr0_rr, const float* Wr0_br,
    const float* Wl0_br, const float* Wr0_rb,
    const float* Wl1_br, const float* Wl1_rr, const float* Wr1_rr, const float* Wr1_br,
    const float* b0_rr, const float* b0_br, const float* b1_rr, const float* b1_br,
    __hip_bfloat16* WT1, __hip_bfloat16* WT2, __hip_bfloat16* WT3, __hip_bfloat16* WT4,
    float* bsum0, float* bsum1)
{
    int job = blockIdx.y;
    int t = blockIdx.x * 256 + threadIdx.x;
    if (job == 8) {
        if (t < 128) bsum0[t] = b0_rr[t] + b0_br[t];
        else if (t < 192) bsum1[t - 128] = b1_rr[t - 128] + b1_br[t - 128];
        return;
    }
    const float* A = nullptr; const float* B = nullptr;
    __hip_bfloat16* dst = nullptr; int dout = 128;
    switch (job) {
        case 0: A = Wl0_rb; dst = WT1;                 break;
        case 1: A = Wl0_rr; dst = WT1 + 128 * 128;     break;
        case 2: A = Wr0_rr; B = Wr0_br; dst = WT1 + 2 * 128 * 128; break;
        case 3: A = Wl0_br; dst = WT2;                 break;
        case 4: A = Wr0_rb; dst = WT2 + 128 * 128;     break;
        case 5: A = Wl1_br; dst = WT3;       dout = 64; break;
        case 6: A = Wl1_rr; dst = WT4;       dout = 64; break;
        case 7: A = Wr1_rr; B = Wr1_br; dst = WT4 + 64 * 128; dout = 64; break;
    }
    if (t >= dout * 128) return;
    int k = t & 127, n = t >> 7;
    float v = A[k * dout + n];
    if (B != nullptr) v += B[k * dout + n];
    dst[n * 128 + k] = __float2bfloat16(v);
}

// ---------------- MFMA GEMMs ----------------
// A staged once in LDS (32 KB -> 4 blocks/CU); B fragments loaded from global
// (weights are L1/L2-resident); internal loop over N-slices reuses staged A.
// 4 waves 2x2, wave tile 64 x (BN/2), 16x16x32 bf16 MFMA.

// Layer 0: BN=128. by=0: A=x_robot (3 slices -> y_rb, y_rr, sr); by=1: A=x_ball (2 -> y_br, sb).
__global__ __launch_bounds__(256, 4) void gemm_l0_kernel(
    const float* __restrict__ xr, const float* __restrict__ xb,
    const __hip_bfloat16* __restrict__ WT1, const __hip_bfloat16* __restrict__ WT2,
    __hip_bfloat16* __restrict__ y_rb, __hip_bfloat16* __restrict__ y_rr,
    __hip_bfloat16* __restrict__ sr,
    __hip_bfloat16* __restrict__ y_br, __hip_bfloat16* __restrict__ sb,
    const float* __restrict__ bsum0, const float* __restrict__ b0_rb)
{
    __shared__ __hip_bfloat16 As[128][136];
    const int tid = threadIdx.x, bm = blockIdx.x, by = blockIdx.y;
    const float* A = (by == 0) ? xr : xb;
    const __hip_bfloat16* WT = (by == 0) ? WT1 : WT2;
    const int ns = (by == 0) ? 3 : 2;
    const int c = tid & 15, rbase = tid >> 4;

    #pragma unroll
    for (int p = 0; p < 8; ++p) {
        int r = p * 16 + rbase;
        int gr = bm * 128 + r;
        float4 u = make_float4(0.f, 0.f, 0.f, 0.f), v = make_float4(0.f, 0.f, 0.f, 0.f);
        if (gr < NRB) {
            const float* src = A + (size_t)gr * 128 + c * 8;
            u = *(const float4*)(src);
            v = *(const float4*)(src + 4);
        }
        __hip_bfloat16* d = &As[r][c * 8];
        d[0] = __float2bfloat16(u.x); d[1] = __float2bfloat16(u.y);
        d[2] = __float2bfloat16(u.z); d[3] = __float2bfloat16(u.w);
        d[4] = __float2bfloat16(v.x); d[5] = __float2bfloat16(v.y);
        d[6] = __float2bfloat16(v.z); d[7] = __float2bfloat16(v.w);
    }
    __syncthreads();

    const int wave = tid >> 6, lane = tid & 63;
    const int wm = wave >> 1, wn = wave & 1;
    const int lrow = lane & 15, lquad = lane >> 4;

    for (int s = 0; s < ns; ++s) {
        const __hip_bfloat16* Wb = WT + (size_t)s * 128 * 128;
        floatx4 acc[4][4];
        #pragma unroll
        for (int mt = 0; mt < 4; ++mt)
            #pragma unroll
            for (int nt = 0; nt < 4; ++nt) acc[mt][nt] = (floatx4){0.f, 0.f, 0.f, 0.f};

        #pragma unroll
        for (int ks = 0; ks < 4; ++ks) {
            short8 bf[4];
            #pragma unroll
            for (int nt = 0; nt < 4; ++nt)
                bf[nt] = *(const short8*)(Wb + (size_t)(wn * 64 + nt * 16 + lrow) * 128 + ks * 32 + lquad * 8);
            #pragma unroll
            for (int mt = 0; mt < 4; ++mt) {
                short8 af = *(const short8*)&As[wm * 64 + mt * 16 + lrow][ks * 32 + lquad * 8];
                #pragma unroll
                for (int nt = 0; nt < 4; ++nt)
                    acc[mt][nt] = __builtin_amdgcn_mfma_f32_16x16x32_bf16(af, bf[nt], acc[mt][nt], 0, 0, 0);
            }
        }

        __hip_bfloat16* op; const float* bp = nullptr;
        if (by == 0) { op = (s == 0) ? y_rb : ((s == 1) ? y_rr : sr); if (s == 2) bp = bsum0; }
        else         { op = (s == 0) ? y_br : sb;                      if (s == 1) bp = b0_rb; }

        #pragma unroll
        for (int mt = 0; mt < 4; ++mt) {
            #pragma unroll
            for (int nt = 0; nt < 4; ++nt) {
                int gcol = wn * 64 + nt * 16 + lrow;
                float bv = (bp != nullptr) ? bp[gcol] : 0.0f;
                #pragma unroll
                for (int r4 = 0; r4 < 4; ++r4) {
                    int grow = bm * 128 + wm * 64 + mt * 16 + lquad * 4 + r4;
                    if (grow < NRB)
                        op[(size_t)grow * 128 + gcol] = __float2bfloat16(acc[mt][nt][r4] + bv);
                }
            }
        }
    }
}

// Layer 1: BN=64, bf16 A. by=0: r@Wl1_rr -> z_rr; by=1: r@Wsum1+bsum1 -> d_out (fp32);
// by=2: bl@Wl1_br -> z_br.
__global__ __launch_bounds__(256, 4) void gemm_l1_kernel(
    const __hip_bfloat16* __restrict__ r, const __hip_bfloat16* __restrict__ bl,
    const __hip_bfloat16* __restrict__ WT3, const __hip_bfloat16* __restrict__ WT4,
    __hip_bfloat16* __restrict__ z_rr, __hip_bfloat16* __restrict__ z_br,
    float* __restrict__ out, const float* __restrict__ bsum1)
{
    __shared__ __hip_bfloat16 As[128][136];
    const int tid = threadIdx.x, bm = blockIdx.x, by = blockIdx.y;
    const __hip_bfloat16* A = (by == 2) ? bl : r;
    const __hip_bfloat16* Wb = (by == 0) ? WT4 : ((by == 1) ? WT4 + 64 * 128 : WT3);
    const int c = tid & 15, rbase = tid >> 4;

    #pragma unroll
    for (int p = 0; p < 8; ++p) {
        int r_ = p * 16 + rbase;
        int gr = bm * 128 + r_;
        int4 u = make_int4(0, 0, 0, 0);
        if (gr < NRB) u = *(const int4*)(A + (size_t)gr * 128 + c * 8);
        *(int4*)&As[r_][c * 8] = u;
    }
    __syncthreads();

    const int wave = tid >> 6, lane = tid & 63;
    const int wm = wave >> 1, wn = wave & 1;
    const int lrow = lane & 15, lquad = lane >> 4;

    floatx4 acc[4][2];
    #pragma unroll
    for (int mt = 0; mt < 4; ++mt)
        #pragma unroll
        for (int nt = 0; nt < 2; ++nt) acc[mt][nt] = (floatx4){0.f, 0.f, 0.f, 0.f};

    #pragma unroll
    for (int ks = 0; ks < 4; ++ks) {
        short8 bf[2];
        #pragma unroll
        for (int nt = 0; nt < 2; ++nt)
            bf[nt] = *(const short8*)(Wb + (size_t)(wn * 32 + nt * 16 + lrow) * 128 + ks * 32 + lquad * 8);
        #pragma unroll
        for (int mt = 0; mt < 4; ++mt) {
            short8 af = *(const short8*)&As[wm * 64 + mt * 16 + lrow][ks * 32 + lquad * 8];
            #pragma unroll
            for (int nt = 0; nt < 2; ++nt)
                acc[mt][nt] = __builtin_amdgcn_mfma_f32_16x16x32_bf16(af, bf[nt], acc[mt][nt], 0, 0, 0);
        }
    }

    #pragma unroll
    for (int mt = 0; mt < 4; ++mt) {
        #pragma unroll
        for (int nt = 0; nt < 2; ++nt) {
            int gcol = wn * 32 + nt * 16 + lrow;
            float bv = (by == 1) ? bsum1[gcol] : 0.0f;
            #pragma unroll
            for (int r4 = 0; r4 < 4; ++r4) {
                int grow = bm * 128 + wm * 64 + mt * 16 + lquad * 4 + r4;
                if (grow < NRB) {
                    float v = acc[mt][nt][r4] + bv;
                    if (by == 1) out[(size_t)grow * 64 + gcol] = v;
                    else if (by == 0) z_rr[(size_t)grow * 64 + gcol] = __float2bfloat16(v);
                    else z_br[(size_t)grow * 64 + gcol] = __float2bfloat16(v);
                }
            }
        }
    }
}

// ---------------- gathers (no atomics, fused epilogues) ----------------

__global__ __launch_bounds__(256) void gather_r_kernel(
    const __hip_bfloat16* __restrict__ y_rr, const __hip_bfloat16* __restrict__ y_br,
    const __hip_bfloat16* __restrict__ sr,
    const int* __restrict__ col, const int* __restrict__ rowstart,
    const float* __restrict__ inv, __hip_bfloat16* __restrict__ r_out)
{
    int row = blockIdx.x * 4 + (threadIdx.x >> 6);
    if (row >= NRB) return;
    int lane = threadIdx.x & 63;
    float2 a = make_float2(0.f, 0.f);
    {
        int s = rowstart[row], e = rowstart[row + 1];
        const __hip_bfloat162* yb = (const __hip_bfloat162*)y_rr;
        int j = s;
        for (; j + 1 < e; j += 2) {
            float2 u = __bfloat1622float2(yb[(size_t)col[j] * 64 + lane]);
            float2 v = __bfloat1622float2(yb[(size_t)col[j + 1] * 64 + lane]);
            a.x += u.x + v.x; a.y += u.y + v.y;
        }
        if (j < e) {
            float2 u = __bfloat1622float2(yb[(size_t)col[j] * 64 + lane]);
            a.x += u.x; a.y += u.y;
        }
    }
    float2 b = make_float2(0.f, 0.f);
    {
        int s = rowstart[200000 + row], e = rowstart[200000 + row + 1];
        const __hip_bfloat162* yb = (const __hip_bfloat162*)y_br;
        int j = s;
        for (; j + 1 < e; j += 2) {
            float2 u = __bfloat1622float2(yb[(size_t)col[j] * 64 + lane]);
            float2 v = __bfloat1622float2(yb[(size_t)col[j + 1] * 64 + lane]);
            b.x += u.x + v.x; b.y += u.y + v.y;
        }
        if (j < e) {
            float2 u = __bfloat1622float2(yb[(size_t)col[j] * 64 + lane]);
            b.x += u.x; b.y += u.y;
        }
    }
    float ia = inv[row], ib = inv[200000 + row];
    float2 s2 = __bfloat1622float2(((const __hip_bfloat162*)sr)[(size_t)row * 64 + lane]);
    __hip_bfloat162 h;
    h.x = __float2bfloat16(fmaxf(ia * a.x + ib * b.x + s2.x, 0.f));
    h.y = __float2bfloat16(fmaxf(ia * a.y + ib * b.y + s2.y, 0.f));
    ((__hip_bfloat162*)r_out)[(size_t)row * 64 + lane] = h;
}

__global__ __launch_bounds__(256) void gather_bl_kernel(
    const __hip_bfloat16* __restrict__ y_rb, const __hip_bfloat16* __restrict__ sb,
    const int* __restrict__ col, const int* __restrict__ rowstart,
    const float* __restrict__ inv, __hip_bfloat16* __restrict__ bl_out)
{
    int row = blockIdx.x * 4 + (threadIdx.x >> 6);
    if (row >= NBL) return;
    int lane = threadIdx.x & 63;
    float2 a = make_float2(0.f, 0.f);
    int s = rowstart[100000 + row], e = rowstart[100000 + row + 1];
    const __hip_bfloat162* yb = (const __hip_bfloat162*)y_rb;
    int j = s;
    for (; j + 1 < e; j += 2) {
        float2 u = __bfloat1622float2(yb[(size_t)col[j] * 64 + lane]);
        float2 v = __bfloat1622float2(yb[(size_t)col[j + 1] * 64 + lane]);
        a.x += u.x + v.x; a.y += u.y + v.y;
    }
    if (j < e) {
        float2 u = __bfloat1622float2(yb[(size_t)col[j] * 64 + lane]);
        a.x += u.x; a.y += u.y;
    }
    float ia = inv[100000 + row];
    float2 s2 = __bfloat1622float2(((const __hip_bfloat162*)sb)[(size_t)row * 64 + lane]);
    __hip_bfloat162 h;
    h.x = __float2bfloat16(fmaxf(ia * a.x + s2.x, 0.f));
    h.y = __float2bfloat16(fmaxf(ia * a.y + s2.y, 0.f));
    ((__hip_bfloat162*)bl_out)[(size_t)row * 64 + lane] = h;
}

__global__ __launch_bounds__(256) void gather64_dual_kernel(
    const __hip_bfloat16* __restrict__ zrr, const __hip_bfloat16* __restrict__ zbr,
    const int* __restrict__ col, const int* __restrict__ rowstart,
    const float* __restrict__ inv, float* __restrict__ out)
{
    int row = blockIdx.x * 4 + (threadIdx.x >> 6);
    if (row >= NRB) return;
    int lane = threadIdx.x & 63;
    int half = lane >> 5, c = lane & 31;

    float2 accA = make_float2(0.f, 0.f);
    {
        int s = rowstart[row], e = rowstart[row + 1];
        const __hip_bfloat162* zb = (const __hip_bfloat162*)zrr;
        for (int j = s + half; j < e; j += 2) {
            float2 a = __bfloat1622float2(zb[(size_t)col[j] * 32 + c]);
            accA.x += a.x; accA.y += a.y;
        }
    }
    float2 accB = make_float2(0.f, 0.f);
    {
        int s = rowstart[200000 + row], e = rowstart[200000 + row + 1];
        const __hip_bfloat162* zb = (const __hip_bfloat162*)zbr;
        for (int j = s + half; j < e; j += 2) {
            float2 a = __bfloat1622float2(zb[(size_t)col[j] * 32 + c]);
            accB.x += a.x; accB.y += a.y;
        }
    }
    float ia = inv[row], ib = inv[200000 + row];
    float2 t;
    t.x = ia * accA.x + ib * accB.x;
    t.y = ia * accA.y + ib * accB.y;
    t.x += __shfl_xor(t.x, 32, 64);
    t.y += __shfl_xor(t.y, 32, 64);
    if (half == 0) {
        float2* op = (float2*)(out + (size_t)row * 64 + c * 2);
        float2 cur = *op;
        cur.x += t.x; cur.y += t.y;
        *op = cur;
    }
}

// ---------------- launch ----------------

extern "C" void kernel_launch(void* const* d_in, const int* in_sizes, int n_in,
                              void* d_out, int out_size, void* d_ws, size_t ws_size,
                              hipStream_t stream) {
    (void)in_sizes; (void)n_in; (void)out_size; (void)ws_size;

    const float* x_robot = (const float*)d_in[0];
    const float* x_ball  = (const float*)d_in[1];
    const int* ei_rr = (const int*)d_in[2];   // [2, E] int32
    const int* ei_rb = (const int*)d_in[3];
    const int* ei_br = (const int*)d_in[4];
    const float* Wl0_rr = (const float*)d_in[5];
    const float* Wr0_rr = (const float*)d_in[6];
    const float* b0_rr  = (const float*)d_in[7];
    const float* Wl0_rb = (const float*)d_in[8];
    const float* Wr0_rb = (const float*)d_in[9];
    const float* b0_rb  = (const float*)d_in[10];
    const float* Wl0_br = (const float*)d_in[11];
    const float* Wr0_br = (const float*)d_in[12];
    const float* b0_br  = (const float*)d_in[13];
    const float* Wl1_rr = (const float*)d_in[14];
    const float* Wr1_rr = (const float*)d_in[15];
    const float* b1_rr  = (const float*)d_in[16];
    // d_in[17..19] unused (ball output not returned)
    const float* Wl1_br = (const float*)d_in[20];
    const float* Wr1_br = (const float*)d_in[21];
    const float* b1_br  = (const float*)d_in[22];

    const size_t NBIG = (size_t)NRB * 128;
    __hip_bfloat16* S0 = (__hip_bfloat16*)d_ws;    // y_rb, later z_br
    __hip_bfloat16* S1 = S0 + NBIG;                // y_rr, later z_rr
    __hip_bfloat16* S2 = S1 + NBIG;                // y_br
    __hip_bfloat16* S3 = S2 + NBIG;                // sr, later bl
    __hip_bfloat16* S4 = S3 + NBIG;                // sb
    __hip_bfloat16* S5 = S4 + NBIG;                // r
    __hip_bfloat16* WT1 = S5 + NBIG;               // 384*128
    __hip_bfloat16* WT2 = WT1 + 384 * 128;         // 256*128
    __hip_bfloat16* WT3 = WT2 + 256 * 128;         // 64*128
    __hip_bfloat16* WT4 = WT3 + 64 * 128;          // 128*128
    int* col_all  = (int*)(WT4 + 128 * 128);       // 3*NEDGE
    int* deg      = col_all + 3 * NEDGE;           // NSEG
    int* cursor   = deg + NSEG;                    // NSEG (adjacent: one memset)
    int* rowstart = cursor + NSEG;                 // NSEG+32
    int* bsum     = rowstart + NSEG + 32;          // 512
    float* inv    = (float*)(bsum + 512);          // NSEG
    float* bsum0  = inv + NSEG;                    // 128
    float* bsum1  = bsum0 + 128;                   // 64

    __hip_bfloat16* y_rb = S0; __hip_bfloat16* z_br = S0;
    __hip_bfloat16* y_rr = S1; __hip_bfloat16* z_rr = S1;
    __hip_bfloat16* y_br = S2;
    __hip_bfloat16* sr = S3;   __hip_bfloat16* bl = S3;
    __hip_bfloat16* sb = S4;
    __hip_bfloat16* r  = S5;

    const int SCAN_BLOCKS = (NSEG + 1024) / 1024;  // 293
    const int eblocks = (NEDGE + 255) / 256;       // 2344
    const int gm = (NRB + 127) / 128;              // 782
    const int rblocks = (NRB + 3) / 4;

    // ---- CSR build ----
    hipMemsetAsync(deg, 0, 2 * NSEG * sizeof(int), stream);
    deg_all_kernel<<<dim3(eblocks, 3), 256, 0, stream>>>(ei_rr, ei_rb, ei_br, deg);
    scan1_kernel<<<SCAN_BLOCKS, 256, 0, stream>>>(deg, rowstart, bsum);
    scan2_kernel<<<1, 512, 0, stream>>>(bsum, SCAN_BLOCKS);
    scan3_inv_kernel<<<SCAN_BLOCKS, 256, 0, stream>>>(rowstart, bsum, deg, inv);
    fill_all_kernel<<<dim3(eblocks, 3), 256, 0, stream>>>(ei_rr, ei_rb, ei_br,
        rowstart, cursor, col_all);

    // ---- weight prep (one launch) ----
    wprep_all_kernel<<<dim3(64, 9), 256, 0, stream>>>(
        Wl0_rb, Wl0_rr, Wr0_rr, Wr0_br, Wl0_br, Wr0_rb,
        Wl1_br, Wl1_rr, Wr1_rr, Wr1_br,
        b0_rr, b0_br, b1_rr, b1_br,
        WT1, WT2, WT3, WT4, bsum0, bsum1);

    // ---- layer 0: both input GEMM groups in one launch ----
    gemm_l0_kernel<<<dim3(gm, 2), 256, 0, stream>>>(x_robot, x_ball, WT1, WT2,
        y_rb, y_rr, sr, y_br, sb, bsum0, b0_rb);
    // r = relu(mean_rr(y_rr) + mean_br(y_br) + sr)
    gather_r_kernel<<<rblocks, 256, 0, stream>>>(y_rr, y_br, sr, col_all, rowstart, inv, r);
    // bl = relu(mean_rb(y_rb) + sb)
    gather_bl_kernel<<<rblocks, 256, 0, stream>>>(y_rb, sb, col_all, rowstart, inv, bl);

    // ---- layer 1: z_rr, out-self, z_br in one launch ----
    gemm_l1_kernel<<<dim3(gm, 3), 256, 0, stream>>>(r, bl, WT3, WT4, z_rr, z_br,
        (float*)d_out, bsum1);
    // out += mean_rr(z_rr) + mean_br(z_br)
    gather64_dual_kernel<<<rblocks, 256, 0, stream>>>(z_rr, z_br, col_all, rowstart,
        inv, (float*)d_out);
}

// Round 7
// 641.799 us; speedup vs baseline: 7.3969x; 1.2057x over previous
//
#include <hip/hip_runtime.h>
#include <hip/hip_bf16.h>
#include <cstddef>

#define NRB 100000      // robot nodes
#define NBL 100000      // ball nodes
#define NEDGE 600000    // edges per edge type
#define NSEG 300000     // concatenated dst space: [rr | rb | br], 100k each
// dims: 128 -> 128 -> 64
// NOTE: harness delivers integer inputs as int32 (edge indices are const int*).

typedef __attribute__((ext_vector_type(8))) short short8;
typedef __attribute__((ext_vector_type(4))) float floatx4;

// ---------------- CSR build (merged) ----------------

__global__ __launch_bounds__(256) void deg_all_kernel(const int* __restrict__ ei0,
                                                      const int* __restrict__ ei1,
                                                      const int* __restrict__ ei2,
                                                      int* __restrict__ deg) {
    int e = blockIdx.x * 256 + threadIdx.x;
    if (e >= NEDGE) return;
    const int* ei = (blockIdx.y == 0) ? ei0 : ((blockIdx.y == 1) ? ei1 : ei2);
    atomicAdd(&deg[blockIdx.y * 100000 + ei[NEDGE + e]], 1);
}

__global__ __launch_bounds__(256) void scan1_kernel(const int* __restrict__ deg,
                                                    int* __restrict__ rowstart,
                                                    int* __restrict__ bsum) {
    __shared__ int sh[256];
    int t = threadIdx.x, blk = blockIdx.x;
    int base = blk * 1024 + t * 4;
    int v0 = (base + 0 < NSEG) ? deg[base + 0] : 0;
    int v1 = (base + 1 < NSEG) ? deg[base + 1] : 0;
    int v2 = (base + 2 < NSEG) ? deg[base + 2] : 0;
    int v3 = (base + 3 < NSEG) ? deg[base + 3] : 0;
    int tsum = v0 + v1 + v2 + v3;
    sh[t] = tsum; __syncthreads();
    for (int off = 1; off < 256; off <<= 1) {
        int x = (t >= off) ? sh[t - off] : 0;
        __syncthreads();
        sh[t] += x;
        __syncthreads();
    }
    int excl = sh[t] - tsum;
    if (t == 255) bsum[blk] = sh[255];
    if (base + 0 <= NSEG) rowstart[base + 0] = excl;
    if (base + 1 <= NSEG) rowstart[base + 1] = excl + v0;
    if (base + 2 <= NSEG) rowstart[base + 2] = excl + v0 + v1;
    if (base + 3 <= NSEG) rowstart[base + 3] = excl + v0 + v1 + v2;
}

__global__ __launch_bounds__(512) void scan2_kernel(int* __restrict__ bsum, int nb) {
    __shared__ int sh[512];
    int t = threadIdx.x;
    int v = (t < nb) ? bsum[t] : 0;
    sh[t] = v; __syncthreads();
    for (int off = 1; off < 512; off <<= 1) {
        int x = (t >= off) ? sh[t - off] : 0;
        __syncthreads();
        sh[t] += x;
        __syncthreads();
    }
    if (t < nb) bsum[t] = sh[t] - v;   // exclusive
}

__global__ __launch_bounds__(256) void scan3_inv_kernel(int* __restrict__ rowstart,
                                                        const int* __restrict__ bsum,
                                                        const int* __restrict__ deg,
                                                        float* __restrict__ inv) {
    int t = threadIdx.x, blk = blockIdx.x;
    int add = bsum[blk];
    int base = blk * 1024 + t * 4;
    #pragma unroll
    for (int j = 0; j < 4; ++j) {
        if (base + j <= NSEG) rowstart[base + j] += add;
        if (base + j < NSEG) inv[base + j] = 1.0f / fmaxf((float)deg[base + j], 1.0f);
    }
}

__global__ __launch_bounds__(256) void fill_all_kernel(const int* __restrict__ ei0,
                                                       const int* __restrict__ ei1,
                                                       const int* __restrict__ ei2,
                                                       const int* __restrict__ rowstart,
                                                       int* __restrict__ cursor,
                                                       int* __restrict__ col) {
    int e = blockIdx.x * 256 + threadIdx.x;
    if (e >= NEDGE) return;
    const int* ei = (blockIdx.y == 0) ? ei0 : ((blockIdx.y == 1) ? ei1 : ei2);
    int src = ei[e];
    int g = blockIdx.y * 100000 + ei[NEDGE + e];
    int pos = atomicAdd(&cursor[g], 1);
    col[rowstart[g] + pos] = src;
}

// ---------------- weight prep (one launch) ----------------
__global__ __launch_bounds__(256) void wprep_all_kernel(
    const float* Wl0_rb, const float* Wl0_rr, const float* Wr0_rr, const float* Wr0_br,
    const float* Wl0_br, const float* Wr0_rb,
    const float* Wl1_br, const float* Wl1_rr, const float* Wr1_rr, const float* Wr1_br,
    const float* b0_rr, const float* b0_br, const float* b1_rr, const float* b1_br,
    __hip_bfloat16* WT1, __hip_bfloat16* WT2, __hip_bfloat16* WT3, __hip_bfloat16* WT4,
    float* bsum0, float* bsum1)
{
    int job = blockIdx.y;
    int t = blockIdx.x * 256 + threadIdx.x;
    if (job == 8) {
        if (t < 128) bsum0[t] = b0_rr[t] + b0_br[t];
        else if (t < 192) bsum1[t - 128] = b1_rr[t - 128] + b1_br[t - 128];
        return;
    }
    const float* A = nullptr; const float* B = nullptr;
    __hip_bfloat16* dst = nullptr; int dout = 128;
    switch (job) {
        case 0: A = Wl0_rb; dst = WT1;                 break;
        case 1: A = Wl0_rr; dst = WT1 + 128 * 128;     break;
        case 2: A = Wr0_rr; B = Wr0_br; dst = WT1 + 2 * 128 * 128; break;
        case 3: A = Wl0_br; dst = WT2;                 break;
        case 4: A = Wr0_rb; dst = WT2 + 128 * 128;     break;
        case 5: A = Wl1_br; dst = WT3;       dout = 64; break;
        case 6: A = Wl1_rr; dst = WT4;       dout = 64; break;
        case 7: A = Wr1_rr; B = Wr1_br; dst = WT4 + 64 * 128; dout = 64; break;
    }
    if (t >= dout * 128) return;
    int k = t & 127, n = t >> 7;
    float v = A[k * dout + n];
    if (B != nullptr) v += B[k * dout + n];
    dst[n * 128 + k] = __float2bfloat16(v);
}

// ---------------- MFMA GEMMs ----------------
// A staged once in LDS; B fragments from global (L2-resident weights); slice loop
// reuses staged A. Epilogue goes through a per-wave LDS transpose so global
// stores are 16B/lane, 128B-contiguous per 8-lane group (no partial-line RMW).

union Pack8 { __hip_bfloat16 h[8]; int4 v; };

// Layer 0: BN=128. by=0: A=x_robot (3 slices -> y_rb, y_rr, sr); by=1: A=x_ball (2 -> y_br, sb).
__global__ __launch_bounds__(256, 3) void gemm_l0_kernel(
    const float* __restrict__ xr, const float* __restrict__ xb,
    const __hip_bfloat16* __restrict__ WT1, const __hip_bfloat16* __restrict__ WT2,
    __hip_bfloat16* __restrict__ y_rb, __hip_bfloat16* __restrict__ y_rr,
    __hip_bfloat16* __restrict__ sr,
    __hip_bfloat16* __restrict__ y_br, __hip_bfloat16* __restrict__ sb,
    const float* __restrict__ bsum0, const float* __restrict__ b0_rb)
{
    __shared__ __hip_bfloat16 As[128][136];
    __shared__ float Es[4][16][68];   // per-wave epilogue stage (stride 272B: 16B-aligned rows)
    const int tid = threadIdx.x, bm = blockIdx.x, by = blockIdx.y;
    const float* A = (by == 0) ? xr : xb;
    const __hip_bfloat16* WT = (by == 0) ? WT1 : WT2;
    const int ns = (by == 0) ? 3 : 2;
    const int c = tid & 15, rbase = tid >> 4;

    #pragma unroll
    for (int p = 0; p < 8; ++p) {
        int r = p * 16 + rbase;
        int gr = bm * 128 + r;
        float4 u = make_float4(0.f, 0.f, 0.f, 0.f), v = make_float4(0.f, 0.f, 0.f, 0.f);
        if (gr < NRB) {
            const float* src = A + (size_t)gr * 128 + c * 8;
            u = *(const float4*)(src);
            v = *(const float4*)(src + 4);
        }
        __hip_bfloat16* d = &As[r][c * 8];
        d[0] = __float2bfloat16(u.x); d[1] = __float2bfloat16(u.y);
        d[2] = __float2bfloat16(u.z); d[3] = __float2bfloat16(u.w);
        d[4] = __float2bfloat16(v.x); d[5] = __float2bfloat16(v.y);
        d[6] = __float2bfloat16(v.z); d[7] = __float2bfloat16(v.w);
    }
    __syncthreads();

    const int wave = tid >> 6, lane = tid & 63;
    const int wm = wave >> 1, wn = wave & 1;
    const int lrow = lane & 15, lquad = lane >> 4;

    for (int s = 0; s < ns; ++s) {
        const __hip_bfloat16* Wb = WT + (size_t)s * 128 * 128;
        floatx4 acc[4][4];
        #pragma unroll
        for (int mt = 0; mt < 4; ++mt)
            #pragma unroll
            for (int nt = 0; nt < 4; ++nt) acc[mt][nt] = (floatx4){0.f, 0.f, 0.f, 0.f};

        #pragma unroll
        for (int ks = 0; ks < 4; ++ks) {
            short8 bf[4];
            #pragma unroll
            for (int nt = 0; nt < 4; ++nt)
                bf[nt] = *(const short8*)(Wb + (size_t)(wn * 64 + nt * 16 + lrow) * 128 + ks * 32 + lquad * 8);
            #pragma unroll
            for (int mt = 0; mt < 4; ++mt) {
                short8 af = *(const short8*)&As[wm * 64 + mt * 16 + lrow][ks * 32 + lquad * 8];
                #pragma unroll
                for (int nt = 0; nt < 4; ++nt)
                    acc[mt][nt] = __builtin_amdgcn_mfma_f32_16x16x32_bf16(af, bf[nt], acc[mt][nt], 0, 0, 0);
            }
        }

        __hip_bfloat16* op; const float* bp = nullptr;
        if (by == 0) { op = (s == 0) ? y_rb : ((s == 1) ? y_rr : sr); if (s == 2) bp = bsum0; }
        else         { op = (s == 0) ? y_br : sb;                      if (s == 1) bp = b0_rb; }

        float bv[4];
        #pragma unroll
        for (int nt = 0; nt < 4; ++nt)
            bv[nt] = (bp != nullptr) ? bp[wn * 64 + nt * 16 + lrow] : 0.0f;

        #pragma unroll
        for (int mt = 0; mt < 4; ++mt) {
            // stage wave's 16x64 fp32 tile (same-wave LDS ops are in-order)
            #pragma unroll
            for (int nt = 0; nt < 4; ++nt)
                #pragma unroll
                for (int r4 = 0; r4 < 4; ++r4)
                    Es[wave][lquad * 4 + r4][nt * 16 + lrow] = acc[mt][nt][r4] + bv[nt];
            // read back row-contiguous, store 16B/lane (8 lanes = 128B row)
            #pragma unroll
            for (int it = 0; it < 2; ++it) {
                int row = it * 8 + (lane >> 3);
                int ch = lane & 7;
                float4 u = *(const float4*)&Es[wave][row][ch * 8];
                float4 v = *(const float4*)&Es[wave][row][ch * 8 + 4];
                int grow = bm * 128 + wm * 64 + mt * 16 + row;
                if (grow < NRB) {
                    Pack8 pk;
                    pk.h[0] = __float2bfloat16(u.x); pk.h[1] = __float2bfloat16(u.y);
                    pk.h[2] = __float2bfloat16(u.z); pk.h[3] = __float2bfloat16(u.w);
                    pk.h[4] = __float2bfloat16(v.x); pk.h[5] = __float2bfloat16(v.y);
                    pk.h[6] = __float2bfloat16(v.z); pk.h[7] = __float2bfloat16(v.w);
                    *(int4*)(op + (size_t)grow * 128 + wn * 64 + ch * 8) = pk.v;
                }
            }
        }
    }
}

// Layer 1: BN=64. by=0: A=r, slices {z_rr (bf16), out=r@Wsum1+bsum1 (fp32)};
// by=1: A=bl, slice {z_br (bf16)}.
__global__ __launch_bounds__(256, 3) void gemm_l1_kernel(
    const __hip_bfloat16* __restrict__ r, const __hip_bfloat16* __restrict__ bl,
    const __hip_bfloat16* __restrict__ WT3, const __hip_bfloat16* __restrict__ WT4,
    __hip_bfloat16* __restrict__ z_rr, __hip_bfloat16* __restrict__ z_br,
    float* __restrict__ out, const float* __restrict__ bsum1)
{
    __shared__ __hip_bfloat16 As[128][136];
    __shared__ float Es[4][16][36];
    const int tid = threadIdx.x, bm = blockIdx.x, by = blockIdx.y;
    const __hip_bfloat16* A = (by == 0) ? r : bl;
    const int ns = (by == 0) ? 2 : 1;
    const int c = tid & 15, rbase = tid >> 4;

    #pragma unroll
    for (int p = 0; p < 8; ++p) {
        int r_ = p * 16 + rbase;
        int gr = bm * 128 + r_;
        int4 u = make_int4(0, 0, 0, 0);
        if (gr < NRB) u = *(const int4*)(A + (size_t)gr * 128 + c * 8);
        *(int4*)&As[r_][c * 8] = u;
    }
    __syncthreads();

    const int wave = tid >> 6, lane = tid & 63;
    const int wm = wave >> 1, wn = wave & 1;
    const int lrow = lane & 15, lquad = lane >> 4;

    for (int s = 0; s < ns; ++s) {
        const __hip_bfloat16* Wb = (by == 1) ? WT3 : ((s == 0) ? WT4 : WT4 + 64 * 128);
        floatx4 acc[4][2];
        #pragma unroll
        for (int mt = 0; mt < 4; ++mt)
            #pragma unroll
            for (int nt = 0; nt < 2; ++nt) acc[mt][nt] = (floatx4){0.f, 0.f, 0.f, 0.f};

        #pragma unroll
        for (int ks = 0; ks < 4; ++ks) {
            short8 bf[2];
            #pragma unroll
            for (int nt = 0; nt < 2; ++nt)
                bf[nt] = *(const short8*)(Wb + (size_t)(wn * 32 + nt * 16 + lrow) * 128 + ks * 32 + lquad * 8);
            #pragma unroll
            for (int mt = 0; mt < 4; ++mt) {
                short8 af = *(const short8*)&As[wm * 64 + mt * 16 + lrow][ks * 32 + lquad * 8];
                #pragma unroll
                for (int nt = 0; nt < 2; ++nt)
                    acc[mt][nt] = __builtin_amdgcn_mfma_f32_16x16x32_bf16(af, bf[nt], acc[mt][nt], 0, 0, 0);
            }
        }

        const bool isf = (by == 0 && s == 1);
        float bv[2];
        #pragma unroll
        for (int nt = 0; nt < 2; ++nt)
            bv[nt] = isf ? bsum1[wn * 32 + nt * 16 + lrow] : 0.0f;

        #pragma unroll
        for (int mt = 0; mt < 4; ++mt) {
            #pragma unroll
            for (int nt = 0; nt < 2; ++nt)
                #pragma unroll
                for (int r4 = 0; r4 < 4; ++r4)
                    Es[wave][lquad * 4 + r4][nt * 16 + lrow] = acc[mt][nt][r4] + bv[nt];
            int row = lane >> 2, ch = lane & 3;
            float4 u = *(const float4*)&Es[wave][row][ch * 8];
            float4 v = *(const float4*)&Es[wave][row][ch * 8 + 4];
            int grow = bm * 128 + wm * 64 + mt * 16 + row;
            if (grow < NRB) {
                if (isf) {
                    float* p = out + (size_t)grow * 64 + wn * 32 + ch * 8;
                    *(float4*)p = u;
                    *(float4*)(p + 4) = v;
                } else {
                    __hip_bfloat16* op = (by == 0) ? z_rr : z_br;
                    Pack8 pk;
                    pk.h[0] = __float2bfloat16(u.x); pk.h[1] = __float2bfloat16(u.y);
                    pk.h[2] = __float2bfloat16(u.z); pk.h[3] = __float2bfloat16(u.w);
                    pk.h[4] = __float2bfloat16(v.x); pk.h[5] = __float2bfloat16(v.y);
                    pk.h[6] = __float2bfloat16(v.z); pk.h[7] = __float2bfloat16(v.w);
                    *(int4*)(op + (size_t)grow * 64 + wn * 32 + ch * 8) = pk.v;
                }
            }
        }
    }
}

// ---------------- gathers (no atomics, fused epilogues) ----------------
// by=0: r[row] = relu(inv_rr*sum y_rr + inv_br*sum y_br + sr)
// by=1: bl[row] = relu(inv_rb*sum y_rb + sb)
__global__ __launch_bounds__(256) void gather_l0_kernel(
    const __hip_bfloat16* __restrict__ y_rr, const __hip_bfloat16* __restrict__ y_br,
    const __hip_bfloat16* __restrict__ sr,
    const __hip_bfloat16* __restrict__ y_rb, const __hip_bfloat16* __restrict__ sb,
    const int* __restrict__ col, const int* __restrict__ rowstart,
    const float* __restrict__ inv,
    __hip_bfloat16* __restrict__ r_out, __hip_bfloat16* __restrict__ bl_out)
{
    int row = blockIdx.x * 4 + (threadIdx.x >> 6);
    if (row >= NRB) return;
    int lane = threadIdx.x & 63;

    if (blockIdx.y == 0) {
        float2 a = make_float2(0.f, 0.f);
        {
            int s = rowstart[row], e = rowstart[row + 1];
            const __hip_bfloat162* yb = (const __hip_bfloat162*)y_rr;
            int j = s;
            for (; j + 1 < e; j += 2) {
                float2 u = __bfloat1622float2(yb[(size_t)col[j] * 64 + lane]);
                float2 v = __bfloat1622float2(yb[(size_t)col[j + 1] * 64 + lane]);
                a.x += u.x + v.x; a.y += u.y + v.y;
            }
            if (j < e) {
                float2 u = __bfloat1622float2(yb[(size_t)col[j] * 64 + lane]);
                a.x += u.x; a.y += u.y;
            }
        }
        float2 b = make_float2(0.f, 0.f);
        {
            int s = rowstart[200000 + row], e = rowstart[200000 + row + 1];
            const __hip_bfloat162* yb = (const __hip_bfloat162*)y_br;
            int j = s;
            for (; j + 1 < e; j += 2) {
                float2 u = __bfloat1622float2(yb[(size_t)col[j] * 64 + lane]);
                float2 v = __bfloat1622float2(yb[(size_t)col[j + 1] * 64 + lane]);
                b.x += u.x + v.x; b.y += u.y + v.y;
            }
            if (j < e) {
                float2 u = __bfloat1622float2(yb[(size_t)col[j] * 64 + lane]);
                b.x += u.x; b.y += u.y;
            }
        }
        float ia = inv[row], ib = inv[200000 + row];
        float2 s2 = __bfloat1622float2(((const __hip_bfloat162*)sr)[(size_t)row * 64 + lane]);
        __hip_bfloat162 h;
        h.x = __float2bfloat16(fmaxf(ia * a.x + ib * b.x + s2.x, 0.f));
        h.y = __float2bfloat16(fmaxf(ia * a.y + ib * b.y + s2.y, 0.f));
        ((__hip_bfloat162*)r_out)[(size_t)row * 64 + lane] = h;
    } else {
        float2 a = make_float2(0.f, 0.f);
        int s = rowstart[100000 + row], e = rowstart[100000 + row + 1];
        const __hip_bfloat162* yb = (const __hip_bfloat162*)y_rb;
        int j = s;
        for (; j + 1 < e; j += 2) {
            float2 u = __bfloat1622float2(yb[(size_t)col[j] * 64 + lane]);
            float2 v = __bfloat1622float2(yb[(size_t)col[j + 1] * 64 + lane]);
            a.x += u.x + v.x; a.y += u.y + v.y;
        }
        if (j < e) {
            float2 u = __bfloat1622float2(yb[(size_t)col[j] * 64 + lane]);
            a.x += u.x; a.y += u.y;
        }
        float ia = inv[100000 + row];
        float2 s2 = __bfloat1622float2(((const __hip_bfloat162*)sb)[(size_t)row * 64 + lane]);
        __hip_bfloat162 h;
        h.x = __float2bfloat16(fmaxf(ia * a.x + s2.x, 0.f));
        h.y = __float2bfloat16(fmaxf(ia * a.y + s2.y, 0.f));
        ((__hip_bfloat162*)bl_out)[(size_t)row * 64 + lane] = h;
    }
}

__global__ __launch_bounds__(256) void gather64_dual_kernel(
    const __hip_bfloat16* __restrict__ zrr, const __hip_bfloat16* __restrict__ zbr,
    const int* __restrict__ col, const int* __restrict__ rowstart,
    const float* __restrict__ inv, float* __restrict__ out)
{
    int row = blockIdx.x * 4 + (threadIdx.x >> 6);
    if (row >= NRB) return;
    int lane = threadIdx.x & 63;
    int half = lane >> 5, c = lane & 31;

    float2 accA = make_float2(0.f, 0.f);
    {
        int s = rowstart[row], e = rowstart[row + 1];
        const __hip_bfloat162* zb = (const __hip_bfloat162*)zrr;
        for (int j = s + half; j < e; j += 2) {
            float2 a = __bfloat1622float2(zb[(size_t)col[j] * 32 + c]);
            accA.x += a.x; accA.y += a.y;
        }
    }
    float2 accB = make_float2(0.f, 0.f);
    {
        int s = rowstart[200000 + row], e = rowstart[200000 + row + 1];
        const __hip_bfloat162* zb = (const __hip_bfloat162*)zbr;
        for (int j = s + half; j < e; j += 2) {
            float2 a = __bfloat1622float2(zb[(size_t)col[j] * 32 + c]);
            accB.x += a.x; accB.y += a.y;
        }
    }
    float ia = inv[row], ib = inv[200000 + row];
    float2 t;
    t.x = ia * accA.x + ib * accB.x;
    t.y = ia * accA.y + ib * accB.y;
    t.x += __shfl_xor(t.x, 32, 64);
    t.y += __shfl_xor(t.y, 32, 64);
    if (half == 0) {
        float2* op = (float2*)(out + (size_t)row * 64 + c * 2);
        float2 cur = *op;
        cur.x += t.x; cur.y += t.y;
        *op = cur;
    }
}

// ---------------- launch ----------------

extern "C" void kernel_launch(void* const* d_in, const int* in_sizes, int n_in,
                              void* d_out, int out_size, void* d_ws, size_t ws_size,
                              hipStream_t stream) {
    (void)in_sizes; (void)n_in; (void)out_size; (void)ws_size;

    const float* x_robot = (const float*)d_in[0];
    const float* x_ball  = (const float*)d_in[1];
    const int* ei_rr = (const int*)d_in[2];   // [2, E] int32
    const int* ei_rb = (const int*)d_in[3];
    const int* ei_br = (const int*)d_in[4];
    const float* Wl0_rr = (const float*)d_in[5];
    const float* Wr0_rr = (const float*)d_in[6];
    const float* b0_rr  = (const float*)d_in[7];
    const float* Wl0_rb = (const float*)d_in[8];
    const float* Wr0_rb = (const float*)d_in[9];
    const float* b0_rb  = (const float*)d_in[10];
    const float* Wl0_br = (const float*)d_in[11];
    const float* Wr0_br = (const float*)d_in[12];
    const float* b0_br  = (const float*)d_in[13];
    const float* Wl1_rr = (const float*)d_in[14];
    const float* Wr1_rr = (const float*)d_in[15];
    const float* b1_rr  = (const float*)d_in[16];
    // d_in[17..19] unused (ball output not returned)
    const float* Wl1_br = (const float*)d_in[20];
    const float* Wr1_br = (const float*)d_in[21];
    const float* b1_br  = (const float*)d_in[22];

    const size_t NBIG = (size_t)NRB * 128;
    __hip_bfloat16* S0 = (__hip_bfloat16*)d_ws;    // y_rb, later z_br
    __hip_bfloat16* S1 = S0 + NBIG;                // y_rr, later z_rr
    __hip_bfloat16* S2 = S1 + NBIG;                // y_br
    __hip_bfloat16* S3 = S2 + NBIG;                // sr, later bl
    __hip_bfloat16* S4 = S3 + NBIG;                // sb
    __hip_bfloat16* S5 = S4 + NBIG;                // r
    __hip_bfloat16* WT1 = S5 + NBIG;               // 384*128
    __hip_bfloat16* WT2 = WT1 + 384 * 128;         // 256*128
    __hip_bfloat16* WT3 = WT2 + 256 * 128;         // 64*128
    __hip_bfloat16* WT4 = WT3 + 64 * 128;          // 128*128
    int* col_all  = (int*)(WT4 + 128 * 128);       // 3*NEDGE
    int* deg      = col_all + 3 * NEDGE;           // NSEG
    int* cursor   = deg + NSEG;                    // NSEG (adjacent: one memset)
    int* rowstart = cursor + NSEG;                 // NSEG+32
    int* bsum     = rowstart + NSEG + 32;          // 512
    float* inv    = (float*)(bsum + 512);          // NSEG
    float* bsum0  = inv + NSEG;                    // 128
    float* bsum1  = bsum0 + 128;                   // 64

    __hip_bfloat16* y_rb = S0; __hip_bfloat16* z_br = S0;
    __hip_bfloat16* y_rr = S1; __hip_bfloat16* z_rr = S1;
    __hip_bfloat16* y_br = S2;
    __hip_bfloat16* sr = S3;   __hip_bfloat16* bl = S3;
    __hip_bfloat16* sb = S4;
    __hip_bfloat16* r  = S5;

    const int SCAN_BLOCKS = (NSEG + 1024) / 1024;  // 293
    const int eblocks = (NEDGE + 255) / 256;       // 2344
    const int gm = (NRB + 127) / 128;              // 782
    const int rblocks = (NRB + 3) / 4;

    // ---- CSR build ----
    hipMemsetAsync(deg, 0, 2 * NSEG * sizeof(int), stream);
    deg_all_kernel<<<dim3(eblocks, 3), 256, 0, stream>>>(ei_rr, ei_rb, ei_br, deg);
    scan1_kernel<<<SCAN_BLOCKS, 256, 0, stream>>>(deg, rowstart, bsum);
    scan2_kernel<<<1, 512, 0, stream>>>(bsum, SCAN_BLOCKS);
    scan3_inv_kernel<<<SCAN_BLOCKS, 256, 0, stream>>>(rowstart, bsum, deg, inv);
    fill_all_kernel<<<dim3(eblocks, 3), 256, 0, stream>>>(ei_rr, ei_rb, ei_br,
        rowstart, cursor, col_all);

    // ---- weight prep ----
    wprep_all_kernel<<<dim3(64, 9), 256, 0, stream>>>(
        Wl0_rb, Wl0_rr, Wr0_rr, Wr0_br, Wl0_br, Wr0_rb,
        Wl1_br, Wl1_rr, Wr1_rr, Wr1_br,
        b0_rr, b0_br, b1_rr, b1_br,
        WT1, WT2, WT3, WT4, bsum0, bsum1);

    // ---- layer 0 ----
    gemm_l0_kernel<<<dim3(gm, 2), 256, 0, stream>>>(x_robot, x_ball, WT1, WT2,
        y_rb, y_rr, sr, y_br, sb, bsum0, b0_rb);
    gather_l0_kernel<<<dim3(rblocks, 2), 256, 0, stream>>>(y_rr, y_br, sr, y_rb, sb,
        col_all, rowstart, inv, r, bl);

    // ---- layer 1 ----
    gemm_l1_kernel<<<dim3(gm, 2), 256, 0, stream>>>(r, bl, WT3, WT4, z_rr, z_br,
        (float*)d_out, bsum1);
    gather64_dual_kernel<<<rblocks, 256, 0, stream>>>(z_rr, z_br, col_all, rowstart,
        inv, (float*)d_out);
}

// Round 8
// 587.153 us; speedup vs baseline: 8.0853x; 1.0931x over previous
//
#include <hip/hip_runtime.h>
#include <hip/hip_bf16.h>
#include <cstddef>

#define NRB 100000      // robot nodes
#define NBL 100000      // ball nodes
#define NEDGE 600000    // edges per edge type
#define NSEG 300000     // concatenated dst space: [rr | rb | br], 100k each
// dims: 128 -> 128 -> 64
// NOTE: harness delivers integer inputs as int32 (edge indices are const int*).

typedef __attribute__((ext_vector_type(8))) short short8;
typedef __attribute__((ext_vector_type(4))) float floatx4;

// ---------------- CSR build (merged) ----------------

__global__ __launch_bounds__(256) void deg_all_kernel(const int* __restrict__ ei0,
                                                      const int* __restrict__ ei1,
                                                      const int* __restrict__ ei2,
                                                      int* __restrict__ deg) {
    int e = blockIdx.x * 256 + threadIdx.x;
    if (e >= NEDGE) return;
    const int* ei = (blockIdx.y == 0) ? ei0 : ((blockIdx.y == 1) ? ei1 : ei2);
    atomicAdd(&deg[blockIdx.y * 100000 + ei[NEDGE + e]], 1);
}

__global__ __launch_bounds__(256) void scan1_kernel(const int* __restrict__ deg,
                                                    int* __restrict__ rowstart,
                                                    int* __restrict__ bsum) {
    __shared__ int sh[256];
    int t = threadIdx.x, blk = blockIdx.x;
    int base = blk * 1024 + t * 4;
    int v0 = (base + 0 < NSEG) ? deg[base + 0] : 0;
    int v1 = (base + 1 < NSEG) ? deg[base + 1] : 0;
    int v2 = (base + 2 < NSEG) ? deg[base + 2] : 0;
    int v3 = (base + 3 < NSEG) ? deg[base + 3] : 0;
    int tsum = v0 + v1 + v2 + v3;
    sh[t] = tsum; __syncthreads();
    for (int off = 1; off < 256; off <<= 1) {
        int x = (t >= off) ? sh[t - off] : 0;
        __syncthreads();
        sh[t] += x;
        __syncthreads();
    }
    int excl = sh[t] - tsum;
    if (t == 255) bsum[blk] = sh[255];
    if (base + 0 <= NSEG) rowstart[base + 0] = excl;
    if (base + 1 <= NSEG) rowstart[base + 1] = excl + v0;
    if (base + 2 <= NSEG) rowstart[base + 2] = excl + v0 + v1;
    if (base + 3 <= NSEG) rowstart[base + 3] = excl + v0 + v1 + v2;
}

__global__ __launch_bounds__(512) void scan2_kernel(int* __restrict__ bsum, int nb) {
    __shared__ int sh[512];
    int t = threadIdx.x;
    int v = (t < nb) ? bsum[t] : 0;
    sh[t] = v; __syncthreads();
    for (int off = 1; off < 512; off <<= 1) {
        int x = (t >= off) ? sh[t - off] : 0;
        __syncthreads();
        sh[t] += x;
        __syncthreads();
    }
    if (t < nb) bsum[t] = sh[t] - v;   // exclusive
}

__global__ __launch_bounds__(256) void scan3_inv_kernel(int* __restrict__ rowstart,
                                                        const int* __restrict__ bsum,
                                                        const int* __restrict__ deg,
                                                        float* __restrict__ inv) {
    int t = threadIdx.x, blk = blockIdx.x;
    int add = bsum[blk];
    int base = blk * 1024 + t * 4;
    #pragma unroll
    for (int j = 0; j < 4; ++j) {
        if (base + j <= NSEG) rowstart[base + j] += add;
        if (base + j < NSEG) inv[base + j] = 1.0f / fmaxf((float)deg[base + j], 1.0f);
    }
}

__global__ __launch_bounds__(256) void fill_all_kernel(const int* __restrict__ ei0,
                                                       const int* __restrict__ ei1,
                                                       const int* __restrict__ ei2,
                                                       const int* __restrict__ rowstart,
                                                       int* __restrict__ cursor,
                                                       int* __restrict__ col) {
    int e = blockIdx.x * 256 + threadIdx.x;
    if (e >= NEDGE) return;
    const int* ei = (blockIdx.y == 0) ? ei0 : ((blockIdx.y == 1) ? ei1 : ei2);
    int src = ei[e];
    int g = blockIdx.y * 100000 + ei[NEDGE + e];
    int pos = atomicAdd(&cursor[g], 1);
    col[rowstart[g] + pos] = src;
}

// ---------------- weight prep (one launch) ----------------
__global__ __launch_bounds__(256) void wprep_all_kernel(
    const float* Wl0_rb, const float* Wl0_rr, const float* Wr0_rr, const float* Wr0_br,
    const float* Wl0_br, const float* Wr0_rb,
    const float* Wl1_br, const float* Wl1_rr, const float* Wr1_rr, const float* Wr1_br,
    const float* b0_rr, const float* b0_br, const float* b1_rr, const float* b1_br,
    __hip_bfloat16* WT1, __hip_bfloat16* WT2, __hip_bfloat16* WT3, __hip_bfloat16* WT4,
    float* bsum0, float* bsum1)
{
    int job = blockIdx.y;
    int t = blockIdx.x * 256 + threadIdx.x;
    if (job == 8) {
        if (t < 128) bsum0[t] = b0_rr[t] + b0_br[t];
        else if (t < 192) bsum1[t - 128] = b1_rr[t - 128] + b1_br[t - 128];
        return;
    }
    const float* A = nullptr; const float* B = nullptr;
    __hip_bfloat16* dst = nullptr; int dout = 128;
    switch (job) {
        case 0: A = Wl0_rb; dst = WT1;                 break;
        case 1: A = Wl0_rr; dst = WT1 + 128 * 128;     break;
        case 2: A = Wr0_rr; B = Wr0_br; dst = WT1 + 2 * 128 * 128; break;
        case 3: A = Wl0_br; dst = WT2;                 break;
        case 4: A = Wr0_rb; dst = WT2 + 128 * 128;     break;
        case 5: A = Wl1_br; dst = WT3;       dout = 64; break;
        case 6: A = Wl1_rr; dst = WT4;       dout = 64; break;
        case 7: A = Wr1_rr; B = Wr1_br; dst = WT4 + 64 * 128; dout = 64; break;
    }
    if (t >= dout * 128) return;
    int k = t & 127, n = t >> 7;
    float v = A[k * dout + n];
    if (B != nullptr) v += B[k * dout + n];
    dst[n * 128 + k] = __float2bfloat16(v);
}

// ---------------- MFMA GEMMs ----------------
// A staged once in LDS; B fragments from global (L2-resident weights); slice loop
// reuses staged A. Epilogue goes through a per-wave LDS transpose so global
// stores are 16B/lane, 128B-contiguous per 8-lane group (no partial-line RMW).

union Pack8 { __hip_bfloat16 h[8]; int4 v; };

// Layer 0: BN=128. by=0: A=x_robot (3 slices -> y_rb, y_rr, sr); by=1: A=x_ball (2 -> y_br, sb).
__global__ __launch_bounds__(256, 3) void gemm_l0_kernel(
    const float* __restrict__ xr, const float* __restrict__ xb,
    const __hip_bfloat16* __restrict__ WT1, const __hip_bfloat16* __restrict__ WT2,
    __hip_bfloat16* __restrict__ y_rb, __hip_bfloat16* __restrict__ y_rr,
    __hip_bfloat16* __restrict__ sr,
    __hip_bfloat16* __restrict__ y_br, __hip_bfloat16* __restrict__ sb,
    const float* __restrict__ bsum0, const float* __restrict__ b0_rb)
{
    __shared__ __hip_bfloat16 As[128][136];
    __shared__ float Es[4][16][68];   // per-wave epilogue stage
    const int tid = threadIdx.x, bm = blockIdx.x, by = blockIdx.y;
    const float* A = (by == 0) ? xr : xb;
    const __hip_bfloat16* WT = (by == 0) ? WT1 : WT2;
    const int ns = (by == 0) ? 3 : 2;
    const int c = tid & 15, rbase = tid >> 4;

    #pragma unroll
    for (int p = 0; p < 8; ++p) {
        int r = p * 16 + rbase;
        int gr = bm * 128 + r;
        float4 u = make_float4(0.f, 0.f, 0.f, 0.f), v = make_float4(0.f, 0.f, 0.f, 0.f);
        if (gr < NRB) {
            const float* src = A + (size_t)gr * 128 + c * 8;
            u = *(const float4*)(src);
            v = *(const float4*)(src + 4);
        }
        __hip_bfloat16* d = &As[r][c * 8];
        d[0] = __float2bfloat16(u.x); d[1] = __float2bfloat16(u.y);
        d[2] = __float2bfloat16(u.z); d[3] = __float2bfloat16(u.w);
        d[4] = __float2bfloat16(v.x); d[5] = __float2bfloat16(v.y);
        d[6] = __float2bfloat16(v.z); d[7] = __float2bfloat16(v.w);
    }
    __syncthreads();

    const int wave = tid >> 6, lane = tid & 63;
    const int wm = wave >> 1, wn = wave & 1;
    const int lrow = lane & 15, lquad = lane >> 4;

    for (int s = 0; s < ns; ++s) {
        const __hip_bfloat16* Wb = WT + (size_t)s * 128 * 128;
        floatx4 acc[4][4];
        #pragma unroll
        for (int mt = 0; mt < 4; ++mt)
            #pragma unroll
            for (int nt = 0; nt < 4; ++nt) acc[mt][nt] = (floatx4){0.f, 0.f, 0.f, 0.f};

        #pragma unroll
        for (int ks = 0; ks < 4; ++ks) {
            short8 bf[4];
            #pragma unroll
            for (int nt = 0; nt < 4; ++nt)
                bf[nt] = *(const short8*)(Wb + (size_t)(wn * 64 + nt * 16 + lrow) * 128 + ks * 32 + lquad * 8);
            #pragma unroll
            for (int mt = 0; mt < 4; ++mt) {
                short8 af = *(const short8*)&As[wm * 64 + mt * 16 + lrow][ks * 32 + lquad * 8];
                #pragma unroll
                for (int nt = 0; nt < 4; ++nt)
                    acc[mt][nt] = __builtin_amdgcn_mfma_f32_16x16x32_bf16(af, bf[nt], acc[mt][nt], 0, 0, 0);
            }
        }

        __hip_bfloat16* op; const float* bp = nullptr;
        if (by == 0) { op = (s == 0) ? y_rb : ((s == 1) ? y_rr : sr); if (s == 2) bp = bsum0; }
        else         { op = (s == 0) ? y_br : sb;                      if (s == 1) bp = b0_rb; }

        float bv[4];
        #pragma unroll
        for (int nt = 0; nt < 4; ++nt)
            bv[nt] = (bp != nullptr) ? bp[wn * 64 + nt * 16 + lrow] : 0.0f;

        #pragma unroll
        for (int mt = 0; mt < 4; ++mt) {
            #pragma unroll
            for (int nt = 0; nt < 4; ++nt)
                #pragma unroll
                for (int r4 = 0; r4 < 4; ++r4)
                    Es[wave][lquad * 4 + r4][nt * 16 + lrow] = acc[mt][nt][r4] + bv[nt];
            #pragma unroll
            for (int it = 0; it < 2; ++it) {
                int row = it * 8 + (lane >> 3);
                int ch = lane & 7;
                float4 u = *(const float4*)&Es[wave][row][ch * 8];
                float4 v = *(const float4*)&Es[wave][row][ch * 8 + 4];
                int grow = bm * 128 + wm * 64 + mt * 16 + row;
                if (grow < NRB) {
                    Pack8 pk;
                    pk.h[0] = __float2bfloat16(u.x); pk.h[1] = __float2bfloat16(u.y);
                    pk.h[2] = __float2bfloat16(u.z); pk.h[3] = __float2bfloat16(u.w);
                    pk.h[4] = __float2bfloat16(v.x); pk.h[5] = __float2bfloat16(v.y);
                    pk.h[6] = __float2bfloat16(v.z); pk.h[7] = __float2bfloat16(v.w);
                    *(int4*)(op + (size_t)grow * 128 + wn * 64 + ch * 8) = pk.v;
                }
            }
        }
    }
}

// Layer 1: BN=64. by=0: A=r, slices {z_rr (bf16), out=r@Wsum1+bsum1 (fp32)};
// by=1: A=bl, slice {z_br (bf16)}.
__global__ __launch_bounds__(256, 3) void gemm_l1_kernel(
    const __hip_bfloat16* __restrict__ r, const __hip_bfloat16* __restrict__ bl,
    const __hip_bfloat16* __restrict__ WT3, const __hip_bfloat16* __restrict__ WT4,
    __hip_bfloat16* __restrict__ z_rr, __hip_bfloat16* __restrict__ z_br,
    float* __restrict__ out, const float* __restrict__ bsum1)
{
    __shared__ __hip_bfloat16 As[128][136];
    __shared__ float Es[4][16][36];
    const int tid = threadIdx.x, bm = blockIdx.x, by = blockIdx.y;
    const __hip_bfloat16* A = (by == 0) ? r : bl;
    const int ns = (by == 0) ? 2 : 1;
    const int c = tid & 15, rbase = tid >> 4;

    #pragma unroll
    for (int p = 0; p < 8; ++p) {
        int r_ = p * 16 + rbase;
        int gr = bm * 128 + r_;
        int4 u = make_int4(0, 0, 0, 0);
        if (gr < NRB) u = *(const int4*)(A + (size_t)gr * 128 + c * 8);
        *(int4*)&As[r_][c * 8] = u;
    }
    __syncthreads();

    const int wave = tid >> 6, lane = tid & 63;
    const int wm = wave >> 1, wn = wave & 1;
    const int lrow = lane & 15, lquad = lane >> 4;

    for (int s = 0; s < ns; ++s) {
        const __hip_bfloat16* Wb = (by == 1) ? WT3 : ((s == 0) ? WT4 : WT4 + 64 * 128);
        floatx4 acc[4][2];
        #pragma unroll
        for (int mt = 0; mt < 4; ++mt)
            #pragma unroll
            for (int nt = 0; nt < 2; ++nt) acc[mt][nt] = (floatx4){0.f, 0.f, 0.f, 0.f};

        #pragma unroll
        for (int ks = 0; ks < 4; ++ks) {
            short8 bf[2];
            #pragma unroll
            for (int nt = 0; nt < 2; ++nt)
                bf[nt] = *(const short8*)(Wb + (size_t)(wn * 32 + nt * 16 + lrow) * 128 + ks * 32 + lquad * 8);
            #pragma unroll
            for (int mt = 0; mt < 4; ++mt) {
                short8 af = *(const short8*)&As[wm * 64 + mt * 16 + lrow][ks * 32 + lquad * 8];
                #pragma unroll
                for (int nt = 0; nt < 2; ++nt)
                    acc[mt][nt] = __builtin_amdgcn_mfma_f32_16x16x32_bf16(af, bf[nt], acc[mt][nt], 0, 0, 0);
            }
        }

        const bool isf = (by == 0 && s == 1);
        float bv[2];
        #pragma unroll
        for (int nt = 0; nt < 2; ++nt)
            bv[nt] = isf ? bsum1[wn * 32 + nt * 16 + lrow] : 0.0f;

        #pragma unroll
        for (int mt = 0; mt < 4; ++mt) {
            #pragma unroll
            for (int nt = 0; nt < 2; ++nt)
                #pragma unroll
                for (int r4 = 0; r4 < 4; ++r4)
                    Es[wave][lquad * 4 + r4][nt * 16 + lrow] = acc[mt][nt][r4] + bv[nt];
            int row = lane >> 2, ch = lane & 3;
            float4 u = *(const float4*)&Es[wave][row][ch * 8];
            float4 v = *(const float4*)&Es[wave][row][ch * 8 + 4];
            int grow = bm * 128 + wm * 64 + mt * 16 + row;
            if (grow < NRB) {
                if (isf) {
                    float* p = out + (size_t)grow * 64 + wn * 32 + ch * 8;
                    *(float4*)p = u;
                    *(float4*)(p + 4) = v;
                } else {
                    __hip_bfloat16* op = (by == 0) ? z_rr : z_br;
                    Pack8 pk;
                    pk.h[0] = __float2bfloat16(u.x); pk.h[1] = __float2bfloat16(u.y);
                    pk.h[2] = __float2bfloat16(u.z); pk.h[3] = __float2bfloat16(u.w);
                    pk.h[4] = __float2bfloat16(v.x); pk.h[5] = __float2bfloat16(v.y);
                    pk.h[6] = __float2bfloat16(v.z); pk.h[7] = __float2bfloat16(v.w);
                    *(int4*)(op + (size_t)grow * 64 + wn * 32 + ch * 8) = pk.v;
                }
            }
        }
    }
}

// ---------------- gathers (no atomics, 4-way MLP, fused epilogues) ----------------
// Wave split into 4 groups of 16 lanes; each group walks every 4th neighbor,
// loading a full row (16B/lane for 128-d, 8B/lane for 64-d). rr+br segments
// fused into one loop (per-neighbor scale) so loads pipeline across segments.
// Groups combined with shfl_xor(16), shfl_xor(32).

__device__ inline void facc8(const int4& u, float w, float* a) {
    float2 f0 = __bfloat1622float2(*(const __hip_bfloat162*)&u.x);
    float2 f1 = __bfloat1622float2(*(const __hip_bfloat162*)&u.y);
    float2 f2 = __bfloat1622float2(*(const __hip_bfloat162*)&u.z);
    float2 f3 = __bfloat1622float2(*(const __hip_bfloat162*)&u.w);
    a[0] = fmaf(w, f0.x, a[0]); a[1] = fmaf(w, f0.y, a[1]);
    a[2] = fmaf(w, f1.x, a[2]); a[3] = fmaf(w, f1.y, a[3]);
    a[4] = fmaf(w, f2.x, a[4]); a[5] = fmaf(w, f2.y, a[5]);
    a[6] = fmaf(w, f3.x, a[6]); a[7] = fmaf(w, f3.y, a[7]);
}

__device__ inline void unpack8(const int4& u, float* s) {
    float2 f0 = __bfloat1622float2(*(const __hip_bfloat162*)&u.x);
    float2 f1 = __bfloat1622float2(*(const __hip_bfloat162*)&u.y);
    float2 f2 = __bfloat1622float2(*(const __hip_bfloat162*)&u.z);
    float2 f3 = __bfloat1622float2(*(const __hip_bfloat162*)&u.w);
    s[0] = f0.x; s[1] = f0.y; s[2] = f1.x; s[3] = f1.y;
    s[4] = f2.x; s[5] = f2.y; s[6] = f3.x; s[7] = f3.y;
}

// by=0: r[row] = relu(inv_rr*sum y_rr + inv_br*sum y_br + sr)
// by=1: bl[row] = relu(inv_rb*sum y_rb + sb)
__global__ __launch_bounds__(256) void gather_l0_kernel(
    const __hip_bfloat16* __restrict__ y_rr, const __hip_bfloat16* __restrict__ y_br,
    const __hip_bfloat16* __restrict__ sr,
    const __hip_bfloat16* __restrict__ y_rb, const __hip_bfloat16* __restrict__ sb,
    const int* __restrict__ col, const int* __restrict__ rowstart,
    const float* __restrict__ inv,
    __hip_bfloat16* __restrict__ r_out, __hip_bfloat16* __restrict__ bl_out)
{
    int row = blockIdx.x * 4 + (threadIdx.x >> 6);
    if (row >= NRB) return;
    int lane = threadIdx.x & 63;
    int q = lane >> 4, c = lane & 15;

    float a[8];
    #pragma unroll
    for (int k = 0; k < 8; ++k) a[k] = 0.f;

    const __hip_bfloat16* self;
    __hip_bfloat16* outp;

    if (blockIdx.y == 0) {
        int s1 = rowstart[row],          n1 = rowstart[row + 1] - s1;
        int s2 = rowstart[200000 + row], n2 = rowstart[200000 + row + 1] - s2;
        float ia = inv[row], ib = inv[200000 + row];
        int n = n1 + n2;
        for (int i = q; i < n; i += 4) {
            bool f = i < n1;
            int j = f ? (s1 + i) : (s2 + (i - n1));
            const __hip_bfloat16* yb = f ? y_rr : y_br;
            float w = f ? ia : ib;
            int4 u = *(const int4*)(yb + (size_t)col[j] * 128 + c * 8);
            facc8(u, w, a);
        }
        self = sr; outp = r_out;
    } else {
        int s1 = rowstart[100000 + row], n1 = rowstart[100000 + row + 1] - s1;
        float ia = inv[100000 + row];
        for (int i = q; i < n1; i += 4) {
            int4 u = *(const int4*)(y_rb + (size_t)col[s1 + i] * 128 + c * 8);
            facc8(u, ia, a);
        }
        self = sb; outp = bl_out;
    }

    #pragma unroll
    for (int k = 0; k < 8; ++k) {
        a[k] += __shfl_xor(a[k], 16, 64);
        a[k] += __shfl_xor(a[k], 32, 64);
    }
    if (q == 0) {
        int4 sv = *(const int4*)(self + (size_t)row * 128 + c * 8);
        float s8[8];
        unpack8(sv, s8);
        Pack8 pk;
        #pragma unroll
        for (int k = 0; k < 8; ++k)
            pk.h[k] = __float2bfloat16(fmaxf(a[k] + s8[k], 0.f));
        *(int4*)(outp + (size_t)row * 128 + c * 8) = pk.v;
    }
}

__device__ inline void facc4(const int2& u, float w, float* a) {
    float2 f0 = __bfloat1622float2(*(const __hip_bfloat162*)&u.x);
    float2 f1 = __bfloat1622float2(*(const __hip_bfloat162*)&u.y);
    a[0] = fmaf(w, f0.x, a[0]); a[1] = fmaf(w, f0.y, a[1]);
    a[2] = fmaf(w, f1.x, a[2]); a[3] = fmaf(w, f1.y, a[3]);
}

// out[row] += inv_rr*sum z_rr[col] + inv_br*sum z_br[col]  (64-d)
__global__ __launch_bounds__(256) void gather64_dual_kernel(
    const __hip_bfloat16* __restrict__ zrr, const __hip_bfloat16* __restrict__ zbr,
    const int* __restrict__ col, const int* __restrict__ rowstart,
    const float* __restrict__ inv, float* __restrict__ out)
{
    int row = blockIdx.x * 4 + (threadIdx.x >> 6);
    if (row >= NRB) return;
    int lane = threadIdx.x & 63;
    int q = lane >> 4, c = lane & 15;   // 16 lanes x 8B = 128B row

    float a[4];
    #pragma unroll
    for (int k = 0; k < 4; ++k) a[k] = 0.f;

    int s1 = rowstart[row],          n1 = rowstart[row + 1] - s1;
    int s2 = rowstart[200000 + row], n2 = rowstart[200000 + row + 1] - s2;
    float ia = inv[row], ib = inv[200000 + row];
    int n = n1 + n2;
    for (int i = q; i < n; i += 4) {
        bool f = i < n1;
        int j = f ? (s1 + i) : (s2 + (i - n1));
        const __hip_bfloat16* zb = f ? zrr : zbr;
        float w = f ? ia : ib;
        int2 u = *(const int2*)(zb + (size_t)col[j] * 64 + c * 4);
        facc4(u, w, a);
    }

    #pragma unroll
    for (int k = 0; k < 4; ++k) {
        a[k] += __shfl_xor(a[k], 16, 64);
        a[k] += __shfl_xor(a[k], 32, 64);
    }
    if (q == 0) {
        float4* p = (float4*)(out + (size_t)row * 64 + c * 4);
        float4 cur = *p;
        cur.x += a[0]; cur.y += a[1]; cur.z += a[2]; cur.w += a[3];
        *p = cur;
    }
}

// ---------------- launch ----------------

extern "C" void kernel_launch(void* const* d_in, const int* in_sizes, int n_in,
                              void* d_out, int out_size, void* d_ws, size_t ws_size,
                              hipStream_t stream) {
    (void)in_sizes; (void)n_in; (void)out_size; (void)ws_size;

    const float* x_robot = (const float*)d_in[0];
    const float* x_ball  = (const float*)d_in[1];
    const int* ei_rr = (const int*)d_in[2];   // [2, E] int32
    const int* ei_rb = (const int*)d_in[3];
    const int* ei_br = (const int*)d_in[4];
    const float* Wl0_rr = (const float*)d_in[5];
    const float* Wr0_rr = (const float*)d_in[6];
    const float* b0_rr  = (const float*)d_in[7];
    const float* Wl0_rb = (const float*)d_in[8];
    const float* Wr0_rb = (const float*)d_in[9];
    const float* b0_rb  = (const float*)d_in[10];
    const float* Wl0_br = (const float*)d_in[11];
    const float* Wr0_br = (const float*)d_in[12];
    const float* b0_br  = (const float*)d_in[13];
    const float* Wl1_rr = (const float*)d_in[14];
    const float* Wr1_rr = (const float*)d_in[15];
    const float* b1_rr  = (const float*)d_in[16];
    // d_in[17..19] unused (ball output not returned)
    const float* Wl1_br = (const float*)d_in[20];
    const float* Wr1_br = (const float*)d_in[21];
    const float* b1_br  = (const float*)d_in[22];

    const size_t NBIG = (size_t)NRB * 128;
    __hip_bfloat16* S0 = (__hip_bfloat16*)d_ws;    // y_rb, later z_br
    __hip_bfloat16* S1 = S0 + NBIG;                // y_rr, later z_rr
    __hip_bfloat16* S2 = S1 + NBIG;                // y_br
    __hip_bfloat16* S3 = S2 + NBIG;                // sr, later bl
    __hip_bfloat16* S4 = S3 + NBIG;                // sb
    __hip_bfloat16* S5 = S4 + NBIG;                // r
    __hip_bfloat16* WT1 = S5 + NBIG;               // 384*128
    __hip_bfloat16* WT2 = WT1 + 384 * 128;         // 256*128
    __hip_bfloat16* WT3 = WT2 + 256 * 128;         // 64*128
    __hip_bfloat16* WT4 = WT3 + 64 * 128;          // 128*128
    int* col_all  = (int*)(WT4 + 128 * 128);       // 3*NEDGE
    int* deg      = col_all + 3 * NEDGE;           // NSEG
    int* cursor   = deg + NSEG;                    // NSEG (adjacent: one memset)
    int* rowstart = cursor + NSEG;                 // NSEG+32
    int* bsum     = rowstart + NSEG + 32;          // 512
    float* inv    = (float*)(bsum + 512);          // NSEG
    float* bsum0  = inv + NSEG;                    // 128
    float* bsum1  = bsum0 + 128;                   // 64

    __hip_bfloat16* y_rb = S0; __hip_bfloat16* z_br = S0;
    __hip_bfloat16* y_rr = S1; __hip_bfloat16* z_rr = S1;
    __hip_bfloat16* y_br = S2;
    __hip_bfloat16* sr = S3;   __hip_bfloat16* bl = S3;
    __hip_bfloat16* sb = S4;
    __hip_bfloat16* r  = S5;

    const int SCAN_BLOCKS = (NSEG + 1024) / 1024;  // 293
    const int eblocks = (NEDGE + 255) / 256;       // 2344
    const int gm = (NRB + 127) / 128;              // 782
    const int rblocks = (NRB + 3) / 4;

    // ---- CSR build ----
    hipMemsetAsync(deg, 0, 2 * NSEG * sizeof(int), stream);
    deg_all_kernel<<<dim3(eblocks, 3), 256, 0, stream>>>(ei_rr, ei_rb, ei_br, deg);
    scan1_kernel<<<SCAN_BLOCKS, 256, 0, stream>>>(deg, rowstart, bsum);
    scan2_kernel<<<1, 512, 0, stream>>>(bsum, SCAN_BLOCKS);
    scan3_inv_kernel<<<SCAN_BLOCKS, 256, 0, stream>>>(rowstart, bsum, deg, inv);
    fill_all_kernel<<<dim3(eblocks, 3), 256, 0, stream>>>(ei_rr, ei_rb, ei_br,
        rowstart, cursor, col_all);

    // ---- weight prep ----
    wprep_all_kernel<<<dim3(64, 9), 256, 0, stream>>>(
        Wl0_rb, Wl0_rr, Wr0_rr, Wr0_br, Wl0_br, Wr0_rb,
        Wl1_br, Wl1_rr, Wr1_rr, Wr1_br,
        b0_rr, b0_br, b1_rr, b1_br,
        WT1, WT2, WT3, WT4, bsum0, bsum1);

    // ---- layer 0 ----
    gemm_l0_kernel<<<dim3(gm, 2), 256, 0, stream>>>(x_robot, x_ball, WT1, WT2,
        y_rb, y_rr, sr, y_br, sb, bsum0, b0_rb);
    gather_l0_kernel<<<dim3(rblocks, 2), 256, 0, stream>>>(y_rr, y_br, sr, y_rb, sb,
        col_all, rowstart, inv, r, bl);

    // ---- layer 1 ----
    gemm_l1_kernel<<<dim3(gm, 2), 256, 0, stream>>>(r, bl, WT3, WT4, z_rr, z_br,
        (float*)d_out, bsum1);
    gather64_dual_kernel<<<rblocks, 256, 0, stream>>>(z_rr, z_br, col_all, rowstart,
        inv, (float*)d_out);
}